// Round 10
// baseline (89.053 us; speedup 1.0000x reference)
//
#include <hip/hip_runtime.h>
#include <math.h>

#define BATCH 2
#define SEQ 1024
#define DM 512
#define DI 1024
#define DS 128
#define NH 16
#define HD 64
#define CONVD 1280
#define DPROJ 2320
#define ROWS (BATCH*SEQ)   // 2048
#define NCH 16             // chunks per sequence
#define CHK 64             // chunk length
#define NPAD 2432          // in_proj N padded to 19*128

typedef unsigned short u16;
typedef unsigned int   u32;
typedef u16   u16x4 __attribute__((ext_vector_type(4)));
typedef u16   u16x8 __attribute__((ext_vector_type(8)));
typedef short bf16x8 __attribute__((ext_vector_type(8)));
typedef float f32x4 __attribute__((ext_vector_type(4)));

__device__ __forceinline__ u16 f2bf(float f) {
    u32 u = __float_as_uint(f);
    return (u16)((u + 0x7fffu + ((u >> 16) & 1u)) >> 16);
}
__device__ __forceinline__ float bf2f(u16 h) {
    return __uint_as_float(((u32)h) << 16);
}
__device__ __forceinline__ void gl_lds16(const u16* g, u16* lds) {
    __builtin_amdgcn_global_load_lds((const __attribute__((address_space(1))) void*)g,
                                     (__attribute__((address_space(3))) void*)lds,
                                     16, 0, 0);
}

// bijective XCD-chunked swizzle: grid must be divisible by 8
__device__ __forceinline__ int xcd_swz(int bid, int nwg) {
    int q = nwg >> 3;
    return (bid & 7) * q + (bid >> 3);
}

// swizzled LDS tile: rows x SLROW slots of 8 u16; physical slot = q ^ (row&7)
__device__ __forceinline__ int swz_off(int row, int q, int SLROW) {
    return (row*SLROW + (q ^ (row & 7)))*8;
}
// stage 64 rows x SLROW slots from global (rows gstride u16 apart) into linear LDS
template<int SLROW>
__device__ __forceinline__ void stage64(const u16* gbase, int gstride, u16* lds, int tid) {
    #pragma unroll
    for (int j = 0; j < (64*SLROW)/256; ++j) {
        int slot = j*256 + tid;
        int row = slot / SLROW;
        int pos = slot % SLROW;
        gl_lds16(gbase + (size_t)row*gstride + (pos ^ (row & 7))*8, lds + slot*8);
    }
}

// ---------------- prep: fp32->bf16 conversions + exact-fp32 dt ----------------
__device__ __forceinline__ void cvt_blk(const float* __restrict__ src,
                                        u16* __restrict__ dst,
                                        int blk, int n_src, int n_total) {
    int idx = (blk*256 + threadIdx.x)*8;
    if (idx >= n_total) return;
    u16x8 o;
    if (idx + 8 <= n_src) {
        float4 a = *reinterpret_cast<const float4*>(src + idx);
        float4 b = *reinterpret_cast<const float4*>(src + idx + 4);
        o[0]=f2bf(a.x); o[1]=f2bf(a.y); o[2]=f2bf(a.z); o[3]=f2bf(a.w);
        o[4]=f2bf(b.x); o[5]=f2bf(b.y); o[6]=f2bf(b.z); o[7]=f2bf(b.w);
    } else {
        #pragma unroll
        for (int e = 0; e < 8; ++e)
            o[e] = (idx + e < n_src) ? f2bf(src[idx + e]) : (u16)0;
    }
    *reinterpret_cast<u16x8*>(dst + idx) = o;
}

__global__ __launch_bounds__(256) void k_prep(const float* __restrict__ x,
                                              const float* __restrict__ W,
                                              const float* __restrict__ Wo,
                                              const float* __restrict__ nw,
                                              const float* __restrict__ dt_bias,
                                              const float* __restrict__ A_log,
                                              u16* __restrict__ xb,
                                              u16* __restrict__ Wb,
                                              u16* __restrict__ Wob,
                                              float* __restrict__ dtb,
                                              float* __restrict__ abuf) {
    int bid = blockIdx.x;
    if (bid < 512) { cvt_blk(x, xb, bid, ROWS*DM, ROWS*DM); return; }
    if (bid < 1120) { cvt_blk(W, Wb, bid-512, DPROJ*DM, NPAD*DM); return; }
    if (bid < 1376) {
        // Wob with norm_w folded: Wob[d][e] = Wo[d][e] * nw[e]
        int idx = ((bid-1120)*256 + threadIdx.x)*8;
        int e = idx & (DI-1);
        float4 a = *reinterpret_cast<const float4*>(Wo + idx);
        float4 b = *reinterpret_cast<const float4*>(Wo + idx + 4);
        float4 na = *reinterpret_cast<const float4*>(nw + e);
        float4 nb = *reinterpret_cast<const float4*>(nw + e + 4);
        u16x8 o;
        o[0]=f2bf(a.x*na.x); o[1]=f2bf(a.y*na.y); o[2]=f2bf(a.z*na.z); o[3]=f2bf(a.w*na.w);
        o[4]=f2bf(b.x*nb.x); o[5]=f2bf(b.y*nb.y); o[6]=f2bf(b.z*nb.z); o[7]=f2bf(b.w*nb.w);
        *reinterpret_cast<u16x8*>(Wob + idx) = o;
        return;
    }
    // dt: exact fp32 dot x . W_dt[h]
    int wave = threadIdx.x >> 6, lane = threadIdx.x & 63;
    int row = (bid-1376)*4 + wave;
    int h = lane & 15, part = lane >> 4;
    const float* xr = x + (size_t)row * DM + part*128;
    const float* wr = W + (size_t)(DI + CONVD + h) * DM + part*128;
    float acc = 0.f;
    #pragma unroll 4
    for (int j = 0; j < 32; ++j) {
        float4 xv = *reinterpret_cast<const float4*>(xr + j*4);
        float4 wv = *reinterpret_cast<const float4*>(wr + j*4);
        acc += xv.x*wv.x + xv.y*wv.y + xv.z*wv.z + xv.w*wv.w;
    }
    acc += __shfl_xor(acc, 16);
    acc += __shfl_xor(acc, 32);
    if (part == 0) {
        float v = acc + dt_bias[h];
        float dt = (v > 20.f) ? v : log1pf(expf(v));
        dtb[row*NH + h]  = dt;
        abuf[row*NH + h] = dt * (-expf(A_log[h]));
    }
}

// ---------------- MFMA GEMM, BK=64, double-buffered, XCD-swizzled 1D grid ----------------
template<int BM, int BN, int K, int NBX, bool BF16OUT>
__global__ __launch_bounds__(256) void k_gemm(const u16* __restrict__ A,
                                              const u16* __restrict__ B,
                                              void* __restrict__ Cv,
                                              int ldc, int ncols) {
    constexpr int BK = 64;
    constexpr int NK = K / BK;
    constexpr int WTM = BM/2, WTN = BN/2, FM = WTM/16, FN = WTN/16;
    constexpr int CA = BM/32, CB = BN/32;   // gl_lds chunks per thread per tile
    constexpr int TA = BM*8, TB = BN*8;     // 8-u16 slots per tile
    __shared__ u16 As[2*TA*8];
    __shared__ u16 Bs[2*TB*8];
    int tid = threadIdx.x, lane = tid & 63, wave = tid >> 6;
    int wr = wave >> 1, wc = wave & 1;

    int nb = xcd_swz(blockIdx.x, gridDim.x);
    size_t bm = (size_t)(nb / NBX) * BM, bn = (size_t)(nb % NBX) * BN;

    const u16* sA[CA]; int dA[CA];
    #pragma unroll
    for (int j = 0; j < CA; ++j) {
        int i = j*256 + tid, row = i >> 3, pos = i & 7;
        sA[j] = A + (bm + row)*(size_t)K + (pos ^ (row & 7))*8;
        dA[j] = i*8;
    }
    const u16* sB[CB]; int dB[CB];
    #pragma unroll
    for (int j = 0; j < CB; ++j) {
        int i = j*256 + tid, row = i >> 3, pos = i & 7;
        sB[j] = B + (bn + row)*(size_t)K + (pos ^ (row & 7))*8;
        dB[j] = i*8;
    }

    int fr = lane & 15, kq = lane >> 4;
    int ar[FM], br[FN];
    #pragma unroll
    for (int fi = 0; fi < FM; ++fi) ar[fi] = wr*WTM + fi*16 + fr;
    #pragma unroll
    for (int fj = 0; fj < FN; ++fj) br[fj] = wc*WTN + fj*16 + fr;

    f32x4 acc[FM][FN];
    #pragma unroll
    for (int fi = 0; fi < FM; ++fi)
        #pragma unroll
        for (int fj = 0; fj < FN; ++fj)
            acc[fi][fj] = (f32x4){0.f,0.f,0.f,0.f};

    // prologue stage
    #pragma unroll
    for (int j = 0; j < CA; ++j) gl_lds16(sA[j], As + dA[j]);
    #pragma unroll
    for (int j = 0; j < CB; ++j) gl_lds16(sB[j], Bs + dB[j]);
    asm volatile("s_waitcnt vmcnt(0)" ::: "memory");
    __builtin_amdgcn_s_barrier();

    int cur = 0;
    #pragma unroll 1
    for (int step = 0; step < NK; ++step) {
        if (step + 1 < NK) {
            int k0 = (step+1)*BK;
            int nbuf = cur ^ 1;
            #pragma unroll
            for (int j = 0; j < CA; ++j) gl_lds16(sA[j] + k0, As + nbuf*TA*8 + dA[j]);
            #pragma unroll
            for (int j = 0; j < CB; ++j) gl_lds16(sB[j] + k0, Bs + nbuf*TB*8 + dB[j]);
        }
        const u16* Ab = As + cur*TA*8;
        const u16* Bb = Bs + cur*TB*8;
        #pragma unroll
        for (int ks = 0; ks < 2; ++ks) {
            bf16x8 av[FM], bv[FN];
            #pragma unroll
            for (int fi = 0; fi < FM; ++fi)
                av[fi] = *reinterpret_cast<const bf16x8*>(Ab + (ar[fi]*8 + ((ks*4+kq) ^ (ar[fi]&7)))*8);
            #pragma unroll
            for (int fj = 0; fj < FN; ++fj)
                bv[fj] = *reinterpret_cast<const bf16x8*>(Bb + (br[fj]*8 + ((ks*4+kq) ^ (br[fj]&7)))*8);
            #pragma unroll
            for (int fi = 0; fi < FM; ++fi)
                #pragma unroll
                for (int fj = 0; fj < FN; ++fj)
                    acc[fi][fj] = __builtin_amdgcn_mfma_f32_16x16x32_bf16(
                        av[fi], bv[fj], acc[fi][fj], 0, 0, 0);
        }
        asm volatile("s_waitcnt vmcnt(0)" ::: "memory");
        __builtin_amdgcn_s_barrier();
        cur ^= 1;
    }

    #pragma unroll
    for (int fi = 0; fi < FM; ++fi) {
        size_t grow0 = bm + wr*WTM + fi*16 + kq*4;
        #pragma unroll
        for (int fj = 0; fj < FN; ++fj) {
            size_t gcol = bn + wc*WTN + fj*16 + fr;
            if ((int)gcol < ncols) {
                #pragma unroll
                for (int r = 0; r < 4; ++r) {
                    if constexpr (BF16OUT)
                        ((u16*)Cv)[(grow0 + r)*ldc + gcol] = f2bf(acc[fi][fj][r]);
                    else
                        ((float*)Cv)[(grow0 + r)*ldc + gcol] = acc[fi][fj][r];
                }
            }
        }
    }
}

// ---------------- fused out_proj + gate + RMSNorm ----------------
// out[m][d] = scale[m] * sum_e gg[m][e] * Wob[d][e],  gg = y*silu(z),
// scale[m] = rsqrt(mean_e gg^2 + eps).  nw pre-folded into Wob.
__global__ __launch_bounds__(256) void k_outproj_gate(
    const u16* __restrict__ ybuf, const u16* __restrict__ zxb,
    const u16* __restrict__ Wob, float* __restrict__ out) {
    constexpr int BM=64, BN=64, K=1024, BK=64, NK=K/BK, NBX=DM/BN;
    constexpr int FM=2, FN=2;
    constexpr int TA = BM*8, TB = BN*8;
    __shared__ u16 As[2*TA*8];
    __shared__ u16 Bs[2*TB*8];
    __shared__ float s_ssq[BM];
    int tid = threadIdx.x, lane = tid & 63, wave = tid >> 6;
    int wr = wave >> 1, wc = wave & 1;

    int nb = xcd_swz(blockIdx.x, gridDim.x);
    size_t bm = (size_t)(nb / NBX) * BM, bn = (size_t)(nb % NBX) * BN;

    // A reg-staging: thread handles row r, elems qd*16..qd*16+15 of each BK step
    int r = tid >> 2, qd = tid & 3;
    const u16* yrow = ybuf + (bm + r)*(size_t)DI + qd*16;
    const u16* zrow = zxb + (bm + r)*(size_t)DPROJ + qd*16;
    int aslot0 = (r*8 + ((2*qd)   ^ (r & 7)))*8;
    int aslot1 = (r*8 + ((2*qd+1) ^ (r & 7)))*8;

    // B via global_load_lds
    const u16* sB[2]; int dB[2];
    #pragma unroll
    for (int j = 0; j < 2; ++j) {
        int i = j*256 + tid, row = i >> 3, pos = i & 7;
        sB[j] = Wob + (bn + row)*(size_t)K + (pos ^ (row & 7))*8;
        dB[j] = i*8;
    }

    int fr = lane & 15, kq = lane >> 4;
    int ar[FM], br[FN];
    #pragma unroll
    for (int fi = 0; fi < FM; ++fi) ar[fi] = wr*32 + fi*16 + fr;
    #pragma unroll
    for (int fj = 0; fj < FN; ++fj) br[fj] = wc*32 + fj*16 + fr;

    f32x4 acc[FM][FN];
    #pragma unroll
    for (int fi = 0; fi < FM; ++fi)
        #pragma unroll
        for (int fj = 0; fj < FN; ++fj)
            acc[fi][fj] = (f32x4){0.f,0.f,0.f,0.f};

    float ssq = 0.f;
    auto STAGE_A = [&](int buf, u16x8 ya, u16x8 yb, u16x8 za, u16x8 zb) {
        u16x8 o0, o1;
        #pragma unroll
        for (int e = 0; e < 8; ++e) {
            float y = bf2f(ya[e]), z = bf2f(za[e]);
            float gg = y * (z / (1.f + expf(-z)));
            ssq += gg*gg;
            o0[e] = f2bf(gg);
        }
        #pragma unroll
        for (int e = 0; e < 8; ++e) {
            float y = bf2f(yb[e]), z = bf2f(zb[e]);
            float gg = y * (z / (1.f + expf(-z)));
            ssq += gg*gg;
            o1[e] = f2bf(gg);
        }
        u16* dst = As + buf*TA*8;
        *reinterpret_cast<u16x8*>(dst + aslot0) = o0;
        *reinterpret_cast<u16x8*>(dst + aslot1) = o1;
    };

    // prologue: B0 + A0
    #pragma unroll
    for (int j = 0; j < 2; ++j) gl_lds16(sB[j], Bs + dB[j]);
    {
        u16x8 ya = *reinterpret_cast<const u16x8*>(yrow);
        u16x8 yb = *reinterpret_cast<const u16x8*>(yrow + 8);
        u16x8 za = *reinterpret_cast<const u16x8*>(zrow);
        u16x8 zb = *reinterpret_cast<const u16x8*>(zrow + 8);
        STAGE_A(0, ya, yb, za, zb);
    }
    __syncthreads();

    int cur = 0;
    #pragma unroll 1
    for (int step = 0; step < NK; ++step) {
        u16x8 nya, nyb, nza, nzb;
        bool has_next = (step + 1 < NK);
        if (has_next) {
            int k0 = (step+1)*BK;
            #pragma unroll
            for (int j = 0; j < 2; ++j) gl_lds16(sB[j] + k0, Bs + (cur^1)*TB*8 + dB[j]);
            nya = *reinterpret_cast<const u16x8*>(yrow + k0);
            nyb = *reinterpret_cast<const u16x8*>(yrow + k0 + 8);
            nza = *reinterpret_cast<const u16x8*>(zrow + k0);
            nzb = *reinterpret_cast<const u16x8*>(zrow + k0 + 8);
        }
        const u16* Ab = As + cur*TA*8;
        const u16* Bb = Bs + cur*TB*8;
        #pragma unroll
        for (int ks = 0; ks < 2; ++ks) {
            bf16x8 av[FM], bv[FN];
            #pragma unroll
            for (int fi = 0; fi < FM; ++fi)
                av[fi] = *reinterpret_cast<const bf16x8*>(Ab + (ar[fi]*8 + ((ks*4+kq) ^ (ar[fi]&7)))*8);
            #pragma unroll
            for (int fj = 0; fj < FN; ++fj)
                bv[fj] = *reinterpret_cast<const bf16x8*>(Bb + (br[fj]*8 + ((ks*4+kq) ^ (br[fj]&7)))*8);
            #pragma unroll
            for (int fi = 0; fi < FM; ++fi)
                #pragma unroll
                for (int fj = 0; fj < FN; ++fj)
                    acc[fi][fj] = __builtin_amdgcn_mfma_f32_16x16x32_bf16(
                        av[fi], bv[fj], acc[fi][fj], 0, 0, 0);
        }
        if (has_next) STAGE_A(cur^1, nya, nyb, nza, nzb);
        __syncthreads();
        cur ^= 1;
    }

    // per-row ssq: reduce across the 4 qd-lanes of each row (lanes r*4..r*4+3)
    ssq += __shfl_xor(ssq, 1);
    ssq += __shfl_xor(ssq, 2);
    if (qd == 0) s_ssq[r] = ssq;
    __syncthreads();

    #pragma unroll
    for (int fi = 0; fi < FM; ++fi) {
        #pragma unroll
        for (int rr = 0; rr < 4; ++rr) {
            int lr = wr*32 + fi*16 + kq*4 + rr;
            float scale = rsqrtf(s_ssq[lr]*(1.f/DI) + 1e-5f);
            size_t grow = bm + lr;
            #pragma unroll
            for (int fj = 0; fj < FN; ++fj) {
                size_t gcol = bn + wc*32 + fj*16 + fr;
                out[grow*DM + gcol] = scale * acc[fi][fj][rr];
            }
        }
    }
}

// ---------------- depthwise conv + SiLU (bf16 in/out) ----------------
__global__ __launch_bounds__(320) void k_conv(const u16* __restrict__ zx,
                                              const float* __restrict__ cw,
                                              const float* __restrict__ cb,
                                              u16* __restrict__ convo) {
    int row = blockIdx.x;            // b*SEQ + l
    int l   = row & (SEQ-1);
    int c0  = threadIdx.x * 4;

    const float4* cw4 = reinterpret_cast<const float4*>(cw);
    float4 w0 = cw4[c0+0], w1 = cw4[c0+1], w2 = cw4[c0+2], w3 = cw4[c0+3];
    const float* wa0 = &w0.x; const float* wa1 = &w1.x;
    const float* wa2 = &w2.x; const float* wa3 = &w3.x;

    float4 bv = *reinterpret_cast<const float4*>(cb + c0);
    float acc0 = bv.x, acc1 = bv.y, acc2 = bv.z, acc3 = bv.w;

    #pragma unroll
    for (int k = 0; k < 4; ++k) {
        int lk = l - 3 + k;
        if (lk < 0) continue;
        u16x4 v = *reinterpret_cast<const u16x4*>(zx + (size_t)(row-3+k)*DPROJ + DI + c0);
        acc0 += bf2f(v[0]) * wa0[k];
        acc1 += bf2f(v[1]) * wa1[k];
        acc2 += bf2f(v[2]) * wa2[k];
        acc3 += bf2f(v[3]) * wa3[k];
    }
    u16x4 o;
    o[0] = f2bf(acc0 / (1.f + expf(-acc0)));
    o[1] = f2bf(acc1 / (1.f + expf(-acc1)));
    o[2] = f2bf(acc2 / (1.f + expf(-acc2)));
    o[3] = f2bf(acc3 / (1.f + expf(-acc3)));
    *reinterpret_cast<u16x4*>(convo + (size_t)row*CONVD + c0) = o;
}

// ---------------- chunk state via MFMA: S[p][n] = sum_t coef_t*xs[t,p]*B[t,n] ----------------
__global__ __launch_bounds__(256) void k_chunk_state(
    const u16* __restrict__ convo, const float* __restrict__ dtb,
    const float* __restrict__ abuf, u16* __restrict__ Sb,
    float* __restrict__ Pbuf) {
    int nb = xcd_swz(blockIdx.x, gridDim.x);   // h + NH*(c + NCH*b)
    int h  = nb & (NH-1);
    int c  = (nb >> 4) & (NCH-1);
    int b  = nb >> 8;
    int sidx = c + NCH*(h + NH*b);
    int row0 = b*SEQ + c*CHK;
    int tid = threadIdx.x, lane = tid & 63, wave = tid >> 6;
    int wr = wave >> 1, wc = wave & 1;

    __shared__ u16 xsT[64*64];     // rows p, k=t, SLROW=8
    __shared__ u16 BT[128*64];     // rows n, k=t, SLROW=8
    __shared__ float s_coef[CHK];

    int st = tid >> 2, q = tid & 3;
    const u16* r = convo + (size_t)(row0 + st)*CONVD;
    u16x8 xa = *reinterpret_cast<const u16x8*>(r + h*HD + q*16);
    u16x8 xc = *reinterpret_cast<const u16x8*>(r + h*HD + q*16 + 8);
    u16x8 b0 = *reinterpret_cast<const u16x8*>(r + DI + q*32);
    u16x8 b1 = *reinterpret_cast<const u16x8*>(r + DI + q*32 + 8);
    u16x8 b2 = *reinterpret_cast<const u16x8*>(r + DI + q*32 + 16);
    u16x8 b3 = *reinterpret_cast<const u16x8*>(r + DI + q*32 + 24);

    if (tid < CHK) {
        float v = abuf[(size_t)(row0 + tid)*NH + h];
        #pragma unroll
        for (int off = 1; off < 64; off <<= 1) {
            float o = __shfl_up(v, off);
            if (tid >= off) v += o;
        }
        float vend = __shfl(v, 63);
        float dt = dtb[(size_t)(row0 + tid)*NH + h];
        s_coef[tid] = dt * expf(vend - v);
        if (tid == 63) Pbuf[sidx] = expf(vend);
    }
    __syncthreads();

    float cf = s_coef[st];
    #pragma unroll
    for (int e = 0; e < 16; ++e) {
        int p = q*16 + e;
        u16 xv = (e < 8) ? xa[e] : xc[e-8];
        xsT[(p*8 + ((st>>3) ^ (p&7)))*8 + (st&7)] = f2bf(cf * bf2f(xv));
    }
    #pragma unroll
    for (int e = 0; e < 32; ++e) {
        int n = q*32 + e;
        u16 bvv = (e < 8) ? b0[e] : (e < 16) ? b1[e-8] : (e < 24) ? b2[e-16] : b3[e-24];
        BT[(n*8 + ((st>>3) ^ (n&7)))*8 + (st&7)] = bvv;
    }
    __syncthreads();

    int kq = lane >> 4, fr = lane & 15;
    f32x4 acc[2][4];
    #pragma unroll
    for (int fi = 0; fi < 2; ++fi)
        #pragma unroll
        for (int fj = 0; fj < 4; ++fj)
            acc[fi][fj] = (f32x4){0.f,0.f,0.f,0.f};

    #pragma unroll
    for (int ks = 0; ks < 2; ++ks) {
        bf16x8 av[2], bv[4];
        #pragma unroll
        for (int fi = 0; fi < 2; ++fi)
            av[fi] = *reinterpret_cast<const bf16x8*>(xsT + swz_off(wr*32 + fi*16 + fr, ks*4 + kq, 8));
        #pragma unroll
        for (int fj = 0; fj < 4; ++fj)
            bv[fj] = *reinterpret_cast<const bf16x8*>(BT + swz_off(wc*64 + fj*16 + fr, ks*4 + kq, 8));
        #pragma unroll
        for (int fi = 0; fi < 2; ++fi)
            #pragma unroll
            for (int fj = 0; fj < 4; ++fj)
                acc[fi][fj] = __builtin_amdgcn_mfma_f32_16x16x32_bf16(av[fi], bv[fj], acc[fi][fj], 0,0,0);
    }

    u16* outp = Sb + (size_t)sidx*(HD*DS);
    #pragma unroll
    for (int fi = 0; fi < 2; ++fi)
        #pragma unroll
        for (int rr = 0; rr < 4; ++rr) {
            int p = wr*32 + fi*16 + kq*4 + rr;
            #pragma unroll
            for (int fj = 0; fj < 4; ++fj) {
                int n = wc*64 + fj*16 + fr;
                outp[(size_t)p*DS + n] = f2bf(acc[fi][fj][rr]);
            }
        }
}

// ---------------- state pass: parallel over (bh, 8 segments); loads up-front ----------------
__global__ __launch_bounds__(256) void k_state_pass(u16* __restrict__ Sb,
                                                    const float* __restrict__ Pbuf) {
    int bh = blockIdx.x >> 3, seg = blockIdx.x & 7;
    int off = seg*1024 + threadIdx.x*4;
    u16x4 s[NCH];
    #pragma unroll
    for (int cc = 0; cc < NCH; ++cc)
        s[cc] = *reinterpret_cast<const u16x4*>(Sb + ((size_t)(bh*NCH + cc))*(HD*DS) + off);
    float hr[4] = {0.f,0.f,0.f,0.f};
    #pragma unroll
    for (int cc = 0; cc < NCH; ++cc) {
        u16x4 w = { f2bf(hr[0]), f2bf(hr[1]), f2bf(hr[2]), f2bf(hr[3]) };
        *reinterpret_cast<u16x4*>(Sb + ((size_t)(bh*NCH + cc))*(HD*DS) + off) = w;
        float P = Pbuf[bh*NCH + cc];
        #pragma unroll
        for (int j = 0; j < 4; ++j) hr[j] = hr[j]*P + bf2f(s[cc][j]);
    }
}

// ---------------- chunk output via MFMA (swizzled grid, h low bits) ----------------
__global__ __launch_bounds__(256) void k_chunk_out(
    const u16* __restrict__ convo, const float* __restrict__ dtb,
    const float* __restrict__ abuf, const u16* __restrict__ Sb,
    const float* __restrict__ Dp, u16* __restrict__ ybuf) {
    int nb = xcd_swz(blockIdx.x, gridDim.x);
    int h  = nb & (NH-1);
    int c  = (nb >> 4) & (NCH-1);
    int b  = nb >> 8;
    int sidx = c + NCH*(h + NH*b);
    int row0 = b*SEQ + c*CHK;
    int tid = threadIdx.x, lane = tid & 63, wave = tid >> 6;
    int wr = wave >> 1, wc = wave & 1;

    __shared__ u16 Ct[64*128];     // C rows t, k=n, SLROW=16
    __shared__ u16 Bh[64*128];     // B rows s (phase B) then hin rows p (phase D)
    __shared__ u16 Mt[64*64];      // M' rows t, k=s, SLROW=8
    __shared__ u16 dxT[64*64];     // xs rows p, k=s, SLROW=8
    __shared__ float s_cum[CHK];
    __shared__ float s_dt[CHK];

    const u16* cbase = convo + (size_t)row0*CONVD;

    stage64<16>(cbase + DI + DS, CONVD, Ct, tid);
    stage64<16>(cbase + DI,      CONVD, Bh, tid);

    int st = tid >> 2, q = tid & 3;
    u16x8 xr0 = *reinterpret_cast<const u16x8*>(cbase + (size_t)st*CONVD + h*HD + q*16);
    u16x8 xr1 = *reinterpret_cast<const u16x8*>(cbase + (size_t)st*CONVD + h*HD + q*16 + 8);

    if (tid < CHK) {
        float v = abuf[(size_t)(row0 + tid)*NH + h];
        #pragma unroll
        for (int off = 1; off < 64; off <<= 1) {
            float o = __shfl_up(v, off);
            if (tid >= off) v += o;
        }
        s_cum[tid] = v;
        s_dt[tid] = dtb[(size_t)(row0 + tid)*NH + h];
    }
    __syncthreads();   // B1: Ct/Bh staged, cum/dt ready

    // scatter dxT (raw xs; dt folded into M')
    #pragma unroll
    for (int e = 0; e < 16; ++e) {
        int p = q*16 + e;
        u16 xv = (e < 8) ? xr0[e] : xr1[e-8];
        dxT[(p*8 + ((st>>3) ^ (p&7)))*8 + (st&7)] = xv;
    }

    int kq = lane >> 4, fr = lane & 15;

    // phase B: M[t][s] = C_t . B_s (K=128)
    f32x4 macc[2][2];
    #pragma unroll
    for (int fi = 0; fi < 2; ++fi)
        #pragma unroll
        for (int fj = 0; fj < 2; ++fj)
            macc[fi][fj] = (f32x4){0.f,0.f,0.f,0.f};
    #pragma unroll
    for (int ks = 0; ks < 4; ++ks) {
        bf16x8 av[2], bv[2];
        #pragma unroll
        for (int fi = 0; fi < 2; ++fi)
            av[fi] = *reinterpret_cast<const bf16x8*>(Ct + swz_off(wr*32 + fi*16 + fr, ks*4 + kq, 16));
        #pragma unroll
        for (int fj = 0; fj < 2; ++fj)
            bv[fj] = *reinterpret_cast<const bf16x8*>(Bh + swz_off(wc*32 + fj*16 + fr, ks*4 + kq, 16));
        #pragma unroll
        for (int fi = 0; fi < 2; ++fi)
            #pragma unroll
            for (int fj = 0; fj < 2; ++fj)
                macc[fi][fj] = __builtin_amdgcn_mfma_f32_16x16x32_bf16(av[fi], bv[fj], macc[fi][fj], 0,0,0);
    }

    // mask + decay + dt-fold, scatter M' (bf16)
    #pragma unroll
    for (int fi = 0; fi < 2; ++fi)
        #pragma unroll
        for (int rr = 0; rr < 4; ++rr) {
            int t = wr*32 + fi*16 + kq*4 + rr;
            float cumt = s_cum[t];
            #pragma unroll
            for (int fj = 0; fj < 2; ++fj) {
                int s = wc*32 + fj*16 + fr;
                float val = (s <= t) ? macc[fi][fj][rr] * expf(cumt - s_cum[s]) * s_dt[s] : 0.f;
                Mt[(t*8 + ((s>>3) ^ (t&7)))*8 + (s&7)] = f2bf(val);
            }
        }
    __syncthreads();   // B2: Mt/dxT complete, Bh consumed

    // stage hin into Bh (rows p, k=n)
    stage64<16>(Sb + (size_t)sidx*(HD*DS), DS, Bh, tid);

    // phase C: Y[t][p] = sum_s M'[t][s]*xs[s][p]  (K=64)
    f32x4 accY[2][2];
    #pragma unroll
    for (int fi = 0; fi < 2; ++fi)
        #pragma unroll
        for (int fj = 0; fj < 2; ++fj)
            accY[fi][fj] = (f32x4){0.f,0.f,0.f,0.f};
    #pragma unroll
    for (int ks = 0; ks < 2; ++ks) {
        bf16x8 av[2], bv[2];
        #pragma unroll
        for (int fi = 0; fi < 2; ++fi)
            av[fi] = *reinterpret_cast<const bf16x8*>(Mt + swz_off(wr*32 + fi*16 + fr, ks*4 + kq, 8));
        #pragma unroll
        for (int fj = 0; fj < 2; ++fj)
            bv[fj] = *reinterpret_cast<const bf16x8*>(dxT + swz_off(wc*32 + fj*16 + fr, ks*4 + kq, 8));
        #pragma unroll
        for (int fi = 0; fi < 2; ++fi)
            #pragma unroll
            for (int fj = 0; fj < 2; ++fj)
                accY[fi][fj] = __builtin_amdgcn_mfma_f32_16x16x32_bf16(av[fi], bv[fj], accY[fi][fj], 0,0,0);
    }
    __syncthreads();   // B3: hin staged

    // phase D: cross[t][p] = C_t . hin[p]  (K=128)
    f32x4 accD[2][2];
    #pragma unroll
    for (int fi = 0; fi < 2; ++fi)
        #pragma unroll
        for (int fj = 0; fj < 2; ++fj)
            accD[fi][fj] = (f32x4){0.f,0.f,0.f,0.f};
    #pragma unroll
    for (int ks = 0; ks < 4; ++ks) {
        bf16x8 av[2], bv[2];
        #pragma unroll
        for (int fi = 0; fi < 2; ++fi)
            av[fi] = *reinterpret_cast<const bf16x8*>(Ct + swz_off(wr*32 + fi*16 + fr, ks*4 + kq, 16));
        #pragma unroll
        for (int fj = 0; fj < 2; ++fj)
            bv[fj] = *reinterpret_cast<const bf16x8*>(Bh + swz_off(wc*32 + fj*16 + fr, ks*4 + kq, 16));
        #pragma unroll
        for (int fi = 0; fi < 2; ++fi)
            #pragma unroll
            for (int fj = 0; fj < 2; ++fj)
                accD[fi][fj] = __builtin_amdgcn_mfma_f32_16x16x32_bf16(av[fi], bv[fj], accD[fi][fj], 0,0,0);
    }

    // epilogue: y = Y + e^{cum_t}*cross + D*xs
    float Dv = Dp[h];
    #pragma unroll
    for (int fi = 0; fi < 2; ++fi)
        #pragma unroll
        for (int rr = 0; rr < 4; ++rr) {
            int t = wr*32 + fi*16 + kq*4 + rr;
            float et = expf(s_cum[t]);
            #pragma unroll
            for (int fj = 0; fj < 2; ++fj) {
                int p = wc*32 + fj*16 + fr;
                float xs = bf2f(cbase[(size_t)t*CONVD + h*HD + p]);
                float y = accY[fi][fj][rr] + et*accD[fi][fj][rr] + Dv*xs;
                ybuf[(size_t)(row0 + t)*DI + h*HD + p] = f2bf(y);
            }
        }
}

extern "C" void kernel_launch(void* const* d_in, const int* in_sizes, int n_in,
                              void* d_out, int out_size, void* d_ws, size_t ws_size,
                              hipStream_t stream) {
    const float* x         = (const float*)d_in[0];
    const float* in_proj_w = (const float*)d_in[1];
    const float* conv_w    = (const float*)d_in[2];
    const float* conv_b    = (const float*)d_in[3];
    const float* dt_bias   = (const float*)d_in[4];
    const float* A_log     = (const float*)d_in[5];
    const float* Dp        = (const float*)d_in[6];
    const float* norm_w    = (const float*)d_in[7];
    const float* out_proj_w= (const float*)d_in[8];
    float* out = (float*)d_out;

    char* p = (char*)d_ws;
    u16*   zxb   = (u16*)p;   p += (size_t)ROWS*DPROJ*2;
    u16*   convo = (u16*)p;   p += (size_t)ROWS*CONVD*2;
    float* dtb   = (float*)p; p += (size_t)ROWS*NH*4;
    float* abuf  = (float*)p; p += (size_t)ROWS*NH*4;
    u16*   ybuf  = (u16*)p;   p += (size_t)ROWS*DI*2;
    u16*   xb    = (u16*)p;   p += (size_t)ROWS*DM*2;
    u16*   Wb    = (u16*)p;   p += (size_t)NPAD*DM*2;
    u16*   Wob   = (u16*)p;   p += (size_t)DM*DI*2;
    u16*   Sb    = (u16*)p;   p += (size_t)BATCH*NH*NCH*HD*DS*2;
    float* Pbuf  = (float*)p; p += 512*4;

    k_prep<<<1888, 256, 0, stream>>>(x, in_proj_w, out_proj_w, norm_w, dt_bias, A_log,
                                     xb, Wb, Wob, dtb, abuf);

    // in_proj: M=2048 (BM=64), N=2432 (BN=128), K=512; 1D grid 608 = 8 XCD x 76
    k_gemm<64,128,512,19,true><<<(NPAD/128)*(ROWS/64), 256, 0, stream>>>(xb, Wb, zxb, DPROJ, DPROJ);

    k_conv<<<ROWS, CONVD/4, 0, stream>>>(zxb, conv_w, conv_b, convo);

    k_chunk_state<<<BATCH*NH*NCH, 256, 0, stream>>>(convo, dtb, abuf, Sb, Pbuf);
    k_state_pass <<<BATCH*NH*8, 256, 0, stream>>>(Sb, Pbuf);
    k_chunk_out  <<<BATCH*NH*NCH, 256, 0, stream>>>(convo, dtb, abuf, Sb, Dp, ybuf);

    // fused out_proj + gate + RMSNorm: grid 256 = 8 XCD x 32
    k_outproj_gate<<<(DM/64)*(ROWS/64), 256, 0, stream>>>(ybuf, zxb, Wob, out);
}

// Round 11
// 78.169 us; speedup vs baseline: 1.1392x; 1.1392x over previous
//
#include <hip/hip_runtime.h>
#include <math.h>

#define BATCH 2
#define SEQ 1024
#define DM 512
#define DI 1024
#define DS 128
#define NH 16
#define HD 64
#define CONVD 1280
#define DPROJ 2320
#define ROWS (BATCH*SEQ)   // 2048
#define NCH 16             // chunks per sequence
#define CHK 64             // chunk length
#define NPAD 2432          // in_proj N padded to 19*128

typedef unsigned short u16;
typedef unsigned int   u32;
typedef u16   u16x4 __attribute__((ext_vector_type(4)));
typedef u16   u16x8 __attribute__((ext_vector_type(8)));
typedef short bf16x8 __attribute__((ext_vector_type(8)));
typedef float f32x4 __attribute__((ext_vector_type(4)));

__device__ __forceinline__ u16 f2bf(float f) {
    u32 u = __float_as_uint(f);
    return (u16)((u + 0x7fffu + ((u >> 16) & 1u)) >> 16);
}
__device__ __forceinline__ float bf2f(u16 h) {
    return __uint_as_float(((u32)h) << 16);
}
__device__ __forceinline__ void gl_lds16(const u16* g, u16* lds) {
    __builtin_amdgcn_global_load_lds((const __attribute__((address_space(1))) void*)g,
                                     (__attribute__((address_space(3))) void*)lds,
                                     16, 0, 0);
}

// bijective XCD-chunked swizzle: grid must be divisible by 8
__device__ __forceinline__ int xcd_swz(int bid, int nwg) {
    int q = nwg >> 3;
    return (bid & 7) * q + (bid >> 3);
}

// swizzled LDS tile: rows x SLROW slots of 8 u16; physical slot = q ^ (row&7)
__device__ __forceinline__ int swz_off(int row, int q, int SLROW) {
    return (row*SLROW + (q ^ (row & 7)))*8;
}
// stage 64 rows x SLROW slots from global (rows gstride u16 apart) into linear LDS
template<int SLROW>
__device__ __forceinline__ void stage64(const u16* gbase, int gstride, u16* lds, int tid) {
    #pragma unroll
    for (int j = 0; j < (64*SLROW)/256; ++j) {
        int slot = j*256 + tid;
        int row = slot / SLROW;
        int pos = slot % SLROW;
        gl_lds16(gbase + (size_t)row*gstride + (pos ^ (row & 7))*8, lds + slot*8);
    }
}

// ---------------- prep: fp32->bf16 conversions + exact-fp32 dt ----------------
__device__ __forceinline__ void cvt_blk(const float* __restrict__ src,
                                        u16* __restrict__ dst,
                                        int blk, int n_src, int n_total) {
    int idx = (blk*256 + threadIdx.x)*8;
    if (idx >= n_total) return;
    u16x8 o;
    if (idx + 8 <= n_src) {
        float4 a = *reinterpret_cast<const float4*>(src + idx);
        float4 b = *reinterpret_cast<const float4*>(src + idx + 4);
        o[0]=f2bf(a.x); o[1]=f2bf(a.y); o[2]=f2bf(a.z); o[3]=f2bf(a.w);
        o[4]=f2bf(b.x); o[5]=f2bf(b.y); o[6]=f2bf(b.z); o[7]=f2bf(b.w);
    } else {
        #pragma unroll
        for (int e = 0; e < 8; ++e)
            o[e] = (idx + e < n_src) ? f2bf(src[idx + e]) : (u16)0;
    }
    *reinterpret_cast<u16x8*>(dst + idx) = o;
}

__global__ __launch_bounds__(256) void k_prep(const float* __restrict__ x,
                                              const float* __restrict__ W,
                                              const float* __restrict__ Wo,
                                              const float* __restrict__ dt_bias,
                                              const float* __restrict__ A_log,
                                              u16* __restrict__ xb,
                                              u16* __restrict__ Wb,
                                              u16* __restrict__ Wob,
                                              float* __restrict__ dtb,
                                              float* __restrict__ abuf) {
    int bid = blockIdx.x;
    if (bid < 512) { cvt_blk(x, xb, bid, ROWS*DM, ROWS*DM); return; }
    if (bid < 1120) { cvt_blk(W, Wb, bid-512, DPROJ*DM, NPAD*DM); return; }
    if (bid < 1376) { cvt_blk(Wo, Wob, bid-1120, DM*DI, DM*DI); return; }
    // dt: exact fp32 dot x . W_dt[h]
    int wave = threadIdx.x >> 6, lane = threadIdx.x & 63;
    int row = (bid-1376)*4 + wave;
    int h = lane & 15, part = lane >> 4;
    const float* xr = x + (size_t)row * DM + part*128;
    const float* wr = W + (size_t)(DI + CONVD + h) * DM + part*128;
    float acc = 0.f;
    #pragma unroll 4
    for (int j = 0; j < 32; ++j) {
        float4 xv = *reinterpret_cast<const float4*>(xr + j*4);
        float4 wv = *reinterpret_cast<const float4*>(wr + j*4);
        acc += xv.x*wv.x + xv.y*wv.y + xv.z*wv.z + xv.w*wv.w;
    }
    acc += __shfl_xor(acc, 16);
    acc += __shfl_xor(acc, 32);
    if (part == 0) {
        float v = acc + dt_bias[h];
        float dt = (v > 20.f) ? v : log1pf(expf(v));
        dtb[row*NH + h]  = dt;
        abuf[row*NH + h] = dt * (-expf(A_log[h]));
    }
}

// ---------------- MFMA GEMM, BK=64, double-buffered, XCD-swizzled 1D grid ----------------
template<int BM, int BN, int K, int NBX, bool BF16OUT>
__global__ __launch_bounds__(256) void k_gemm(const u16* __restrict__ A,
                                              const u16* __restrict__ B,
                                              void* __restrict__ Cv,
                                              int ldc, int ncols) {
    constexpr int BK = 64;
    constexpr int NK = K / BK;
    constexpr int WTM = BM/2, WTN = BN/2, FM = WTM/16, FN = WTN/16;
    constexpr int CA = BM/32, CB = BN/32;   // gl_lds chunks per thread per tile
    constexpr int TA = BM*8, TB = BN*8;     // 8-u16 slots per tile
    __shared__ u16 As[2*TA*8];
    __shared__ u16 Bs[2*TB*8];
    int tid = threadIdx.x, lane = tid & 63, wave = tid >> 6;
    int wr = wave >> 1, wc = wave & 1;

    int nb = xcd_swz(blockIdx.x, gridDim.x);
    size_t bm = (size_t)(nb / NBX) * BM, bn = (size_t)(nb % NBX) * BN;

    const u16* sA[CA]; int dA[CA];
    #pragma unroll
    for (int j = 0; j < CA; ++j) {
        int i = j*256 + tid, row = i >> 3, pos = i & 7;
        sA[j] = A + (bm + row)*(size_t)K + (pos ^ (row & 7))*8;
        dA[j] = i*8;
    }
    const u16* sB[CB]; int dB[CB];
    #pragma unroll
    for (int j = 0; j < CB; ++j) {
        int i = j*256 + tid, row = i >> 3, pos = i & 7;
        sB[j] = B + (bn + row)*(size_t)K + (pos ^ (row & 7))*8;
        dB[j] = i*8;
    }

    int fr = lane & 15, kq = lane >> 4;
    int ar[FM], br[FN];
    #pragma unroll
    for (int fi = 0; fi < FM; ++fi) ar[fi] = wr*WTM + fi*16 + fr;
    #pragma unroll
    for (int fj = 0; fj < FN; ++fj) br[fj] = wc*WTN + fj*16 + fr;

    f32x4 acc[FM][FN];
    #pragma unroll
    for (int fi = 0; fi < FM; ++fi)
        #pragma unroll
        for (int fj = 0; fj < FN; ++fj)
            acc[fi][fj] = (f32x4){0.f,0.f,0.f,0.f};

    // prologue stage
    #pragma unroll
    for (int j = 0; j < CA; ++j) gl_lds16(sA[j], As + dA[j]);
    #pragma unroll
    for (int j = 0; j < CB; ++j) gl_lds16(sB[j], Bs + dB[j]);
    asm volatile("s_waitcnt vmcnt(0)" ::: "memory");
    __builtin_amdgcn_s_barrier();

    int cur = 0;
    #pragma unroll 1
    for (int step = 0; step < NK; ++step) {
        if (step + 1 < NK) {
            int k0 = (step+1)*BK;
            int nbuf = cur ^ 1;
            #pragma unroll
            for (int j = 0; j < CA; ++j) gl_lds16(sA[j] + k0, As + nbuf*TA*8 + dA[j]);
            #pragma unroll
            for (int j = 0; j < CB; ++j) gl_lds16(sB[j] + k0, Bs + nbuf*TB*8 + dB[j]);
        }
        const u16* Ab = As + cur*TA*8;
        const u16* Bb = Bs + cur*TB*8;
        #pragma unroll
        for (int ks = 0; ks < 2; ++ks) {
            bf16x8 av[FM], bv[FN];
            #pragma unroll
            for (int fi = 0; fi < FM; ++fi)
                av[fi] = *reinterpret_cast<const bf16x8*>(Ab + (ar[fi]*8 + ((ks*4+kq) ^ (ar[fi]&7)))*8);
            #pragma unroll
            for (int fj = 0; fj < FN; ++fj)
                bv[fj] = *reinterpret_cast<const bf16x8*>(Bb + (br[fj]*8 + ((ks*4+kq) ^ (br[fj]&7)))*8);
            #pragma unroll
            for (int fi = 0; fi < FM; ++fi)
                #pragma unroll
                for (int fj = 0; fj < FN; ++fj)
                    acc[fi][fj] = __builtin_amdgcn_mfma_f32_16x16x32_bf16(
                        av[fi], bv[fj], acc[fi][fj], 0, 0, 0);
        }
        asm volatile("s_waitcnt vmcnt(0)" ::: "memory");
        __builtin_amdgcn_s_barrier();
        cur ^= 1;
    }

    #pragma unroll
    for (int fi = 0; fi < FM; ++fi) {
        size_t grow0 = bm + wr*WTM + fi*16 + kq*4;
        #pragma unroll
        for (int fj = 0; fj < FN; ++fj) {
            size_t gcol = bn + wc*WTN + fj*16 + fr;
            if ((int)gcol < ncols) {
                #pragma unroll
                for (int r = 0; r < 4; ++r) {
                    if constexpr (BF16OUT)
                        ((u16*)Cv)[(grow0 + r)*ldc + gcol] = f2bf(acc[fi][fj][r]);
                    else
                        ((float*)Cv)[(grow0 + r)*ldc + gcol] = acc[fi][fj][r];
                }
            }
        }
    }
}

// ---------------- depthwise conv + SiLU (bf16 in/out) ----------------
__global__ __launch_bounds__(320) void k_conv(const u16* __restrict__ zx,
                                              const float* __restrict__ cw,
                                              const float* __restrict__ cb,
                                              u16* __restrict__ convo) {
    int row = blockIdx.x;            // b*SEQ + l
    int l   = row & (SEQ-1);
    int c0  = threadIdx.x * 4;

    const float4* cw4 = reinterpret_cast<const float4*>(cw);
    float4 w0 = cw4[c0+0], w1 = cw4[c0+1], w2 = cw4[c0+2], w3 = cw4[c0+3];
    const float* wa0 = &w0.x; const float* wa1 = &w1.x;
    const float* wa2 = &w2.x; const float* wa3 = &w3.x;

    float4 bv = *reinterpret_cast<const float4*>(cb + c0);
    float acc0 = bv.x, acc1 = bv.y, acc2 = bv.z, acc3 = bv.w;

    #pragma unroll
    for (int k = 0; k < 4; ++k) {
        int lk = l - 3 + k;
        if (lk < 0) continue;
        u16x4 v = *reinterpret_cast<const u16x4*>(zx + (size_t)(row-3+k)*DPROJ + DI + c0);
        acc0 += bf2f(v[0]) * wa0[k];
        acc1 += bf2f(v[1]) * wa1[k];
        acc2 += bf2f(v[2]) * wa2[k];
        acc3 += bf2f(v[3]) * wa3[k];
    }
    u16x4 o;
    o[0] = f2bf(acc0 / (1.f + expf(-acc0)));
    o[1] = f2bf(acc1 / (1.f + expf(-acc1)));
    o[2] = f2bf(acc2 / (1.f + expf(-acc2)));
    o[3] = f2bf(acc3 / (1.f + expf(-acc3)));
    *reinterpret_cast<u16x4*>(convo + (size_t)row*CONVD + c0) = o;
}

// ---------------- chunk state via MFMA: S[p][n] = sum_t coef_t*xs[t,p]*B[t,n] ----------------
__global__ __launch_bounds__(256) void k_chunk_state(
    const u16* __restrict__ convo, const float* __restrict__ dtb,
    const float* __restrict__ abuf, u16* __restrict__ Sb,
    float* __restrict__ Pbuf) {
    int nb = xcd_swz(blockIdx.x, gridDim.x);   // h + NH*(c + NCH*b)
    int h  = nb & (NH-1);
    int c  = (nb >> 4) & (NCH-1);
    int b  = nb >> 8;
    int sidx = c + NCH*(h + NH*b);
    int row0 = b*SEQ + c*CHK;
    int tid = threadIdx.x, lane = tid & 63, wave = tid >> 6;
    int wr = wave >> 1, wc = wave & 1;

    __shared__ u16 xsT[64*64];     // rows p, k=t, SLROW=8
    __shared__ u16 BT[128*64];     // rows n, k=t, SLROW=8
    __shared__ float s_coef[CHK];

    int st = tid >> 2, q = tid & 3;
    const u16* r = convo + (size_t)(row0 + st)*CONVD;
    u16x8 xa = *reinterpret_cast<const u16x8*>(r + h*HD + q*16);
    u16x8 xc = *reinterpret_cast<const u16x8*>(r + h*HD + q*16 + 8);
    u16x8 b0 = *reinterpret_cast<const u16x8*>(r + DI + q*32);
    u16x8 b1 = *reinterpret_cast<const u16x8*>(r + DI + q*32 + 8);
    u16x8 b2 = *reinterpret_cast<const u16x8*>(r + DI + q*32 + 16);
    u16x8 b3 = *reinterpret_cast<const u16x8*>(r + DI + q*32 + 24);

    if (tid < CHK) {
        float v = abuf[(size_t)(row0 + tid)*NH + h];
        #pragma unroll
        for (int off = 1; off < 64; off <<= 1) {
            float o = __shfl_up(v, off);
            if (tid >= off) v += o;
        }
        float vend = __shfl(v, 63);
        float dt = dtb[(size_t)(row0 + tid)*NH + h];
        s_coef[tid] = dt * expf(vend - v);
        if (tid == 63) Pbuf[sidx] = expf(vend);
    }
    __syncthreads();

    float cf = s_coef[st];
    #pragma unroll
    for (int e = 0; e < 16; ++e) {
        int p = q*16 + e;
        u16 xv = (e < 8) ? xa[e] : xc[e-8];
        xsT[(p*8 + ((st>>3) ^ (p&7)))*8 + (st&7)] = f2bf(cf * bf2f(xv));
    }
    #pragma unroll
    for (int e = 0; e < 32; ++e) {
        int n = q*32 + e;
        u16 bvv = (e < 8) ? b0[e] : (e < 16) ? b1[e-8] : (e < 24) ? b2[e-16] : b3[e-24];
        BT[(n*8 + ((st>>3) ^ (n&7)))*8 + (st&7)] = bvv;
    }
    __syncthreads();

    int kq = lane >> 4, fr = lane & 15;
    f32x4 acc[2][4];
    #pragma unroll
    for (int fi = 0; fi < 2; ++fi)
        #pragma unroll
        for (int fj = 0; fj < 4; ++fj)
            acc[fi][fj] = (f32x4){0.f,0.f,0.f,0.f};

    #pragma unroll
    for (int ks = 0; ks < 2; ++ks) {
        bf16x8 av[2], bv[4];
        #pragma unroll
        for (int fi = 0; fi < 2; ++fi)
            av[fi] = *reinterpret_cast<const bf16x8*>(xsT + swz_off(wr*32 + fi*16 + fr, ks*4 + kq, 8));
        #pragma unroll
        for (int fj = 0; fj < 4; ++fj)
            bv[fj] = *reinterpret_cast<const bf16x8*>(BT + swz_off(wc*64 + fj*16 + fr, ks*4 + kq, 8));
        #pragma unroll
        for (int fi = 0; fi < 2; ++fi)
            #pragma unroll
            for (int fj = 0; fj < 4; ++fj)
                acc[fi][fj] = __builtin_amdgcn_mfma_f32_16x16x32_bf16(av[fi], bv[fj], acc[fi][fj], 0,0,0);
    }

    u16* outp = Sb + (size_t)sidx*(HD*DS);
    #pragma unroll
    for (int fi = 0; fi < 2; ++fi)
        #pragma unroll
        for (int rr = 0; rr < 4; ++rr) {
            int p = wr*32 + fi*16 + kq*4 + rr;
            #pragma unroll
            for (int fj = 0; fj < 4; ++fj) {
                int n = wc*64 + fj*16 + fr;
                outp[(size_t)p*DS + n] = f2bf(acc[fi][fj][rr]);
            }
        }
}

// ---------------- chunk output via MFMA, with inline chunk-scan for h_in ----------------
__global__ __launch_bounds__(256) void k_chunk_out(
    const u16* __restrict__ convo, const float* __restrict__ dtb,
    const float* __restrict__ abuf, const u16* __restrict__ Sb,
    const float* __restrict__ Pbuf,
    const float* __restrict__ Dp, u16* __restrict__ ybuf) {
    int nb = xcd_swz(blockIdx.x, gridDim.x);
    int h  = nb & (NH-1);
    int c  = (nb >> 4) & (NCH-1);
    int b  = nb >> 8;
    int row0 = b*SEQ + c*CHK;
    int tid = threadIdx.x, lane = tid & 63, wave = tid >> 6;
    int wr = wave >> 1, wc = wave & 1;

    __shared__ u16 Ct[64*128];     // C rows t, k=n, SLROW=16
    __shared__ u16 Bh[64*128];     // B rows s (phase B) then hin rows p (phase D)
    __shared__ u16 Mt[64*64];      // M' rows t, k=s, SLROW=8
    __shared__ u16 dxT[64*64];     // xs rows p, k=s, SLROW=8
    __shared__ float s_cum[CHK];
    __shared__ float s_dt[CHK];

    const u16* cbase = convo + (size_t)row0*CONVD;

    stage64<16>(cbase + DI + DS, CONVD, Ct, tid);
    stage64<16>(cbase + DI,      CONVD, Bh, tid);

    int st = tid >> 2, q = tid & 3;
    u16x8 xr0 = *reinterpret_cast<const u16x8*>(cbase + (size_t)st*CONVD + h*HD + q*16);
    u16x8 xr1 = *reinterpret_cast<const u16x8*>(cbase + (size_t)st*CONVD + h*HD + q*16 + 8);

    if (tid < CHK) {
        float v = abuf[(size_t)(row0 + tid)*NH + h];
        #pragma unroll
        for (int off = 1; off < 64; off <<= 1) {
            float o = __shfl_up(v, off);
            if (tid >= off) v += o;
        }
        s_cum[tid] = v;
        s_dt[tid] = dtb[(size_t)(row0 + tid)*NH + h];
    }
    __syncthreads();   // B1: Ct/Bh staged, cum/dt ready

    // scatter dxT (raw xs; dt folded into M')
    #pragma unroll
    for (int e = 0; e < 16; ++e) {
        int p = q*16 + e;
        u16 xv = (e < 8) ? xr0[e] : xr1[e-8];
        dxT[(p*8 + ((st>>3) ^ (p&7)))*8 + (st&7)] = xv;
    }

    int kq = lane >> 4, fr = lane & 15;

    // phase B: M[t][s] = C_t . B_s (K=128)
    f32x4 macc[2][2];
    #pragma unroll
    for (int fi = 0; fi < 2; ++fi)
        #pragma unroll
        for (int fj = 0; fj < 2; ++fj)
            macc[fi][fj] = (f32x4){0.f,0.f,0.f,0.f};
    #pragma unroll
    for (int ks = 0; ks < 4; ++ks) {
        bf16x8 av[2], bv[2];
        #pragma unroll
        for (int fi = 0; fi < 2; ++fi)
            av[fi] = *reinterpret_cast<const bf16x8*>(Ct + swz_off(wr*32 + fi*16 + fr, ks*4 + kq, 16));
        #pragma unroll
        for (int fj = 0; fj < 2; ++fj)
            bv[fj] = *reinterpret_cast<const bf16x8*>(Bh + swz_off(wc*32 + fj*16 + fr, ks*4 + kq, 16));
        #pragma unroll
        for (int fi = 0; fi < 2; ++fi)
            #pragma unroll
            for (int fj = 0; fj < 2; ++fj)
                macc[fi][fj] = __builtin_amdgcn_mfma_f32_16x16x32_bf16(av[fi], bv[fj], macc[fi][fj], 0,0,0);
    }

    // mask + decay + dt-fold, scatter M' (bf16)
    #pragma unroll
    for (int fi = 0; fi < 2; ++fi)
        #pragma unroll
        for (int rr = 0; rr < 4; ++rr) {
            int t = wr*32 + fi*16 + kq*4 + rr;
            float cumt = s_cum[t];
            #pragma unroll
            for (int fj = 0; fj < 2; ++fj) {
                int s = wc*32 + fj*16 + fr;
                float val = (s <= t) ? macc[fi][fj][rr] * expf(cumt - s_cum[s]) * s_dt[s] : 0.f;
                Mt[(t*8 + ((s>>3) ^ (t&7)))*8 + (s&7)] = f2bf(val);
            }
        }
    __syncthreads();   // B2: Mt/dxT complete, Bh consumed

    // inline chunk-scan: hin[p][:] = sum_{cc<c} (prod_{j>cc} P_j) * S_cc[p][:]
    // thread handles 4 Bh slots; weight updated incrementally (no runtime-indexed array)
    {
        int off0[4];
        #pragma unroll
        for (int j = 0; j < 4; ++j) {
            int slot = j*256 + tid;
            int row = slot >> 4, pos = slot & 15;
            off0[j] = row*DS + ((pos ^ (row & 7))*8);
        }
        float accf[4][8];
        #pragma unroll
        for (int j = 0; j < 4; ++j)
            #pragma unroll
            for (int e = 0; e < 8; ++e) accf[j][e] = 0.f;

        const float* Pb = Pbuf + NCH*(h + NH*b);
        const u16* Sbase = Sb + (size_t)(NCH*(h + NH*b))*(HD*DS);
        float w = 1.f;
        #pragma unroll 1
        for (int cc = c-1; cc >= 0; --cc) {
            const u16* sc = Sbase + (size_t)cc*(HD*DS);
            #pragma unroll
            for (int j = 0; j < 4; ++j) {
                u16x8 v = *reinterpret_cast<const u16x8*>(sc + off0[j]);
                #pragma unroll
                for (int e = 0; e < 8; ++e) accf[j][e] += w * bf2f(v[e]);
            }
            w *= Pb[cc];
        }
        #pragma unroll
        for (int j = 0; j < 4; ++j) {
            int slot = j*256 + tid;
            u16x8 o;
            #pragma unroll
            for (int e = 0; e < 8; ++e) o[e] = f2bf(accf[j][e]);
            *reinterpret_cast<u16x8*>(Bh + slot*8) = o;
        }
    }

    // phase C: Y[t][p] = sum_s M'[t][s]*xs[s][p]  (K=64)
    f32x4 accY[2][2];
    #pragma unroll
    for (int fi = 0; fi < 2; ++fi)
        #pragma unroll
        for (int fj = 0; fj < 2; ++fj)
            accY[fi][fj] = (f32x4){0.f,0.f,0.f,0.f};
    #pragma unroll
    for (int ks = 0; ks < 2; ++ks) {
        bf16x8 av[2], bv[2];
        #pragma unroll
        for (int fi = 0; fi < 2; ++fi)
            av[fi] = *reinterpret_cast<const bf16x8*>(Mt + swz_off(wr*32 + fi*16 + fr, ks*4 + kq, 8));
        #pragma unroll
        for (int fj = 0; fj < 2; ++fj)
            bv[fj] = *reinterpret_cast<const bf16x8*>(dxT + swz_off(wc*32 + fj*16 + fr, ks*4 + kq, 8));
        #pragma unroll
        for (int fi = 0; fi < 2; ++fi)
            #pragma unroll
            for (int fj = 0; fj < 2; ++fj)
                accY[fi][fj] = __builtin_amdgcn_mfma_f32_16x16x32_bf16(av[fi], bv[fj], accY[fi][fj], 0,0,0);
    }
    __syncthreads();   // B3: hin written to Bh

    // phase D: cross[t][p] = C_t . hin[p]  (K=128)
    f32x4 accD[2][2];
    #pragma unroll
    for (int fi = 0; fi < 2; ++fi)
        #pragma unroll
        for (int fj = 0; fj < 2; ++fj)
            accD[fi][fj] = (f32x4){0.f,0.f,0.f,0.f};
    #pragma unroll
    for (int ks = 0; ks < 4; ++ks) {
        bf16x8 av[2], bv[2];
        #pragma unroll
        for (int fi = 0; fi < 2; ++fi)
            av[fi] = *reinterpret_cast<const bf16x8*>(Ct + swz_off(wr*32 + fi*16 + fr, ks*4 + kq, 16));
        #pragma unroll
        for (int fj = 0; fj < 2; ++fj)
            bv[fj] = *reinterpret_cast<const bf16x8*>(Bh + swz_off(wc*32 + fj*16 + fr, ks*4 + kq, 16));
        #pragma unroll
        for (int fi = 0; fi < 2; ++fi)
            #pragma unroll
            for (int fj = 0; fj < 2; ++fj)
                accD[fi][fj] = __builtin_amdgcn_mfma_f32_16x16x32_bf16(av[fi], bv[fj], accD[fi][fj], 0,0,0);
    }

    // epilogue: y = Y + e^{cum_t}*cross + D*xs
    float Dv = Dp[h];
    #pragma unroll
    for (int fi = 0; fi < 2; ++fi)
        #pragma unroll
        for (int rr = 0; rr < 4; ++rr) {
            int t = wr*32 + fi*16 + kq*4 + rr;
            float et = expf(s_cum[t]);
            #pragma unroll
            for (int fj = 0; fj < 2; ++fj) {
                int p = wc*32 + fj*16 + fr;
                float xs = bf2f(cbase[(size_t)t*CONVD + h*HD + p]);
                float y = accY[fi][fj][rr] + et*accD[fi][fj][rr] + Dv*xs;
                ybuf[(size_t)(row0 + t)*DI + h*HD + p] = f2bf(y);
            }
        }
}

// ---------------- gate + RMSNorm (bf16 in, bf16 out) ----------------
__global__ __launch_bounds__(256) void k_gate(const u16* __restrict__ zx,
                                              const u16* __restrict__ ybuf,
                                              const float* __restrict__ nw,
                                              u16* __restrict__ g) {
    int row = blockIdx.x;
    int t = threadIdx.x;
    const u16* zr = zx + (size_t)row*DPROJ;
    const u16* yr = ybuf + (size_t)row*DI;

    u16x4 zv = *reinterpret_cast<const u16x4*>(zr + t*4);
    u16x4 yv = *reinterpret_cast<const u16x4*>(yr + t*4);
    float gv[4];
    float ss = 0.f;
    #pragma unroll
    for (int j = 0; j < 4; ++j) {
        float z = bf2f(zv[j]), y = bf2f(yv[j]);
        float sz = z / (1.f + expf(-z));
        float gg = y * sz;
        gv[j] = gg;
        ss += gg*gg;
    }
    ss += __shfl_xor(ss, 1);
    ss += __shfl_xor(ss, 2);
    ss += __shfl_xor(ss, 4);
    ss += __shfl_xor(ss, 8);
    ss += __shfl_xor(ss, 16);
    ss += __shfl_xor(ss, 32);
    __shared__ float ls[4];
    if ((t & 63) == 0) ls[t >> 6] = ss;
    __syncthreads();
    float tot = ls[0] + ls[1] + ls[2] + ls[3];
    float scale = rsqrtf(tot * (1.f/DI) + 1e-5f);

    float4 nv = *reinterpret_cast<const float4*>(nw + t*4);
    const float* na = &nv.x;
    u16x4 og = { f2bf(gv[0]*scale*na[0]), f2bf(gv[1]*scale*na[1]),
                 f2bf(gv[2]*scale*na[2]), f2bf(gv[3]*scale*na[3]) };
    *reinterpret_cast<u16x4*>(g + (size_t)row*DI + t*4) = og;
}

extern "C" void kernel_launch(void* const* d_in, const int* in_sizes, int n_in,
                              void* d_out, int out_size, void* d_ws, size_t ws_size,
                              hipStream_t stream) {
    const float* x         = (const float*)d_in[0];
    const float* in_proj_w = (const float*)d_in[1];
    const float* conv_w    = (const float*)d_in[2];
    const float* conv_b    = (const float*)d_in[3];
    const float* dt_bias   = (const float*)d_in[4];
    const float* A_log     = (const float*)d_in[5];
    const float* Dp        = (const float*)d_in[6];
    const float* norm_w    = (const float*)d_in[7];
    const float* out_proj_w= (const float*)d_in[8];
    float* out = (float*)d_out;

    char* p = (char*)d_ws;
    u16*   zxb   = (u16*)p;   p += (size_t)ROWS*DPROJ*2;
    u16*   convo = (u16*)p;   p += (size_t)ROWS*CONVD*2;
    float* dtb   = (float*)p; p += (size_t)ROWS*NH*4;
    float* abuf  = (float*)p; p += (size_t)ROWS*NH*4;
    u16*   ybuf  = (u16*)p;   p += (size_t)ROWS*DI*2;
    u16*   xb    = (u16*)p;   p += (size_t)ROWS*DM*2;
    u16*   Wb    = (u16*)p;   p += (size_t)NPAD*DM*2;
    u16*   Wob   = (u16*)p;   p += (size_t)DM*DI*2;
    u16*   Sb    = (u16*)p;   p += (size_t)BATCH*NH*NCH*HD*DS*2;
    float* Pbuf  = (float*)p; p += 512*4;
    u16*   gb    = (u16*)p;   p += (size_t)ROWS*DI*2;

    k_prep<<<1888, 256, 0, stream>>>(x, in_proj_w, out_proj_w, dt_bias, A_log,
                                     xb, Wb, Wob, dtb, abuf);

    // in_proj: M=2048 (BM=64), N=2432 (BN=128), K=512; 1D grid 608 = 8 XCD x 76
    k_gemm<64,128,512,19,true><<<(NPAD/128)*(ROWS/64), 256, 0, stream>>>(xb, Wb, zxb, DPROJ, DPROJ);

    k_conv<<<ROWS, CONVD/4, 0, stream>>>(zxb, conv_w, conv_b, convo);

    k_chunk_state<<<BATCH*NH*NCH, 256, 0, stream>>>(convo, dtb, abuf, Sb, Pbuf);
    k_chunk_out  <<<BATCH*NH*NCH, 256, 0, stream>>>(convo, dtb, abuf, Sb, Pbuf, Dp, ybuf);

    k_gate<<<ROWS, 256, 0, stream>>>(zxb, ybuf, norm_w, gb);

    // out_proj: M=2048 (BM=64), N=512 (BN=64), K=1024; 1D grid 256 = 8 XCD x 32
    k_gemm<64,64,1024,8,false><<<(DM/64)*(ROWS/64), 256, 0, stream>>>(gb, Wob, out, DM, DM);
}

// Round 12
// 75.087 us; speedup vs baseline: 1.1860x; 1.0410x over previous
//
#include <hip/hip_runtime.h>
#include <math.h>

#define BATCH 2
#define SEQ 1024
#define DM 512
#define DI 1024
#define DS 128
#define NH 16
#define HD 64
#define CONVD 1280
#define DPROJ 2320
#define ROWS (BATCH*SEQ)   // 2048
#define NCH 16             // chunks per sequence
#define CHK 64             // chunk length
#define NPAD 2432          // in_proj N padded to 19*128

typedef unsigned short u16;
typedef unsigned int   u32;
typedef u16   u16x4 __attribute__((ext_vector_type(4)));
typedef u16   u16x8 __attribute__((ext_vector_type(8)));
typedef short bf16x8 __attribute__((ext_vector_type(8)));
typedef float f32x4 __attribute__((ext_vector_type(4)));

__device__ __forceinline__ u16 f2bf(float f) {
    u32 u = __float_as_uint(f);
    return (u16)((u + 0x7fffu + ((u >> 16) & 1u)) >> 16);
}
__device__ __forceinline__ float bf2f(u16 h) {
    return __uint_as_float(((u32)h) << 16);
}
__device__ __forceinline__ void gl_lds16(const u16* g, u16* lds) {
    __builtin_amdgcn_global_load_lds((const __attribute__((address_space(1))) void*)g,
                                     (__attribute__((address_space(3))) void*)lds,
                                     16, 0, 0);
}

template<int N> __device__ __forceinline__ void wait_vmcnt() {
    if constexpr (N == 0) asm volatile("s_waitcnt vmcnt(0)" ::: "memory");
    else if constexpr (N == 4) asm volatile("s_waitcnt vmcnt(4)" ::: "memory");
    else if constexpr (N == 8) asm volatile("s_waitcnt vmcnt(8)" ::: "memory");
}

// bijective XCD-chunked swizzle: grid must be divisible by 8
__device__ __forceinline__ int xcd_swz(int bid, int nwg) {
    int q = nwg >> 3;
    return (bid & 7) * q + (bid >> 3);
}

// swizzled LDS tile: rows x SLROW slots of 8 u16; physical slot = q ^ (row&7)
__device__ __forceinline__ int swz_off(int row, int q, int SLROW) {
    return (row*SLROW + (q ^ (row & 7)))*8;
}
// stage 64 rows x SLROW slots from global (rows gstride u16 apart) into linear LDS
template<int SLROW>
__device__ __forceinline__ void stage64(const u16* gbase, int gstride, u16* lds, int tid) {
    #pragma unroll
    for (int j = 0; j < (64*SLROW)/256; ++j) {
        int slot = j*256 + tid;
        int row = slot / SLROW;
        int pos = slot % SLROW;
        gl_lds16(gbase + (size_t)row*gstride + (pos ^ (row & 7))*8, lds + slot*8);
    }
}

// ---------------- prep: fp32->bf16 conversions + exact-fp32 dt ----------------
__device__ __forceinline__ void cvt_blk(const float* __restrict__ src,
                                        u16* __restrict__ dst,
                                        int blk, int n_src, int n_total) {
    int idx = (blk*256 + threadIdx.x)*8;
    if (idx >= n_total) return;
    u16x8 o;
    if (idx + 8 <= n_src) {
        float4 a = *reinterpret_cast<const float4*>(src + idx);
        float4 b = *reinterpret_cast<const float4*>(src + idx + 4);
        o[0]=f2bf(a.x); o[1]=f2bf(a.y); o[2]=f2bf(a.z); o[3]=f2bf(a.w);
        o[4]=f2bf(b.x); o[5]=f2bf(b.y); o[6]=f2bf(b.z); o[7]=f2bf(b.w);
    } else {
        #pragma unroll
        for (int e = 0; e < 8; ++e)
            o[e] = (idx + e < n_src) ? f2bf(src[idx + e]) : (u16)0;
    }
    *reinterpret_cast<u16x8*>(dst + idx) = o;
}

__global__ __launch_bounds__(256) void k_prep(const float* __restrict__ x,
                                              const float* __restrict__ W,
                                              const float* __restrict__ Wo,
                                              const float* __restrict__ dt_bias,
                                              const float* __restrict__ A_log,
                                              u16* __restrict__ xb,
                                              u16* __restrict__ Wb,
                                              u16* __restrict__ Wob,
                                              float* __restrict__ dtb,
                                              float* __restrict__ abuf) {
    int bid = blockIdx.x;
    if (bid < 512) { cvt_blk(x, xb, bid, ROWS*DM, ROWS*DM); return; }
    if (bid < 1120) { cvt_blk(W, Wb, bid-512, DPROJ*DM, NPAD*DM); return; }
    if (bid < 1376) { cvt_blk(Wo, Wob, bid-1120, DM*DI, DM*DI); return; }
    // dt: exact fp32 dot x . W_dt[h]
    int wave = threadIdx.x >> 6, lane = threadIdx.x & 63;
    int row = (bid-1376)*4 + wave;
    int h = lane & 15, part = lane >> 4;
    const float* xr = x + (size_t)row * DM + part*128;
    const float* wr = W + (size_t)(DI + CONVD + h) * DM + part*128;
    float acc = 0.f;
    #pragma unroll 4
    for (int j = 0; j < 32; ++j) {
        float4 xv = *reinterpret_cast<const float4*>(xr + j*4);
        float4 wv = *reinterpret_cast<const float4*>(wr + j*4);
        acc += xv.x*wv.x + xv.y*wv.y + xv.z*wv.z + xv.w*wv.w;
    }
    acc += __shfl_xor(acc, 16);
    acc += __shfl_xor(acc, 32);
    if (part == 0) {
        float v = acc + dt_bias[h];
        float dt = (v > 20.f) ? v : log1pf(expf(v));
        dtb[row*NH + h]  = dt;
        abuf[row*NH + h] = dt * (-expf(A_log[h]));
    }
}

// ---------------- MFMA GEMM, BK=64, double-buffered, XCD-swizzled 1D grid ----------------
template<int BM, int BN, int K, int NBX, bool BF16OUT>
__global__ __launch_bounds__(256) void k_gemm(const u16* __restrict__ A,
                                              const u16* __restrict__ B,
                                              void* __restrict__ Cv,
                                              int ldc, int ncols) {
    constexpr int BK = 64;
    constexpr int NK = K / BK;
    constexpr int WTM = BM/2, WTN = BN/2, FM = WTM/16, FN = WTN/16;
    constexpr int CA = BM/32, CB = BN/32;   // gl_lds chunks per thread per tile
    constexpr int TA = BM*8, TB = BN*8;     // 8-u16 slots per tile
    __shared__ u16 As[2*TA*8];
    __shared__ u16 Bs[2*TB*8];
    int tid = threadIdx.x, lane = tid & 63, wave = tid >> 6;
    int wr = wave >> 1, wc = wave & 1;

    int nb = xcd_swz(blockIdx.x, gridDim.x);
    size_t bm = (size_t)(nb / NBX) * BM, bn = (size_t)(nb % NBX) * BN;

    const u16* sA[CA]; int dA[CA];
    #pragma unroll
    for (int j = 0; j < CA; ++j) {
        int i = j*256 + tid, row = i >> 3, pos = i & 7;
        sA[j] = A + (bm + row)*(size_t)K + (pos ^ (row & 7))*8;
        dA[j] = i*8;
    }
    const u16* sB[CB]; int dB[CB];
    #pragma unroll
    for (int j = 0; j < CB; ++j) {
        int i = j*256 + tid, row = i >> 3, pos = i & 7;
        sB[j] = B + (bn + row)*(size_t)K + (pos ^ (row & 7))*8;
        dB[j] = i*8;
    }

    int fr = lane & 15, kq = lane >> 4;
    int ar[FM], br[FN];
    #pragma unroll
    for (int fi = 0; fi < FM; ++fi) ar[fi] = wr*WTM + fi*16 + fr;
    #pragma unroll
    for (int fj = 0; fj < FN; ++fj) br[fj] = wc*WTN + fj*16 + fr;

    f32x4 acc[FM][FN];
    #pragma unroll
    for (int fi = 0; fi < FM; ++fi)
        #pragma unroll
        for (int fj = 0; fj < FN; ++fj)
            acc[fi][fj] = (f32x4){0.f,0.f,0.f,0.f};

    // prologue stage
    #pragma unroll
    for (int j = 0; j < CA; ++j) gl_lds16(sA[j], As + dA[j]);
    #pragma unroll
    for (int j = 0; j < CB; ++j) gl_lds16(sB[j], Bs + dB[j]);
    asm volatile("s_waitcnt vmcnt(0)" ::: "memory");
    __builtin_amdgcn_s_barrier();

    int cur = 0;
    #pragma unroll 1
    for (int step = 0; step < NK; ++step) {
        if (step + 1 < NK) {
            int k0 = (step+1)*BK;
            int nbuf = cur ^ 1;
            #pragma unroll
            for (int j = 0; j < CA; ++j) gl_lds16(sA[j] + k0, As + nbuf*TA*8 + dA[j]);
            #pragma unroll
            for (int j = 0; j < CB; ++j) gl_lds16(sB[j] + k0, Bs + nbuf*TB*8 + dB[j]);
        }
        const u16* Ab = As + cur*TA*8;
        const u16* Bb = Bs + cur*TB*8;
        #pragma unroll
        for (int ks = 0; ks < 2; ++ks) {
            bf16x8 av[FM], bv[FN];
            #pragma unroll
            for (int fi = 0; fi < FM; ++fi)
                av[fi] = *reinterpret_cast<const bf16x8*>(Ab + (ar[fi]*8 + ((ks*4+kq) ^ (ar[fi]&7)))*8);
            #pragma unroll
            for (int fj = 0; fj < FN; ++fj)
                bv[fj] = *reinterpret_cast<const bf16x8*>(Bb + (br[fj]*8 + ((ks*4+kq) ^ (br[fj]&7)))*8);
            #pragma unroll
            for (int fi = 0; fi < FM; ++fi)
                #pragma unroll
                for (int fj = 0; fj < FN; ++fj)
                    acc[fi][fj] = __builtin_amdgcn_mfma_f32_16x16x32_bf16(
                        av[fi], bv[fj], acc[fi][fj], 0, 0, 0);
        }
        asm volatile("s_waitcnt vmcnt(0)" ::: "memory");
        __builtin_amdgcn_s_barrier();
        cur ^= 1;
    }

    #pragma unroll
    for (int fi = 0; fi < FM; ++fi) {
        size_t grow0 = bm + wr*WTM + fi*16 + kq*4;
        #pragma unroll
        for (int fj = 0; fj < FN; ++fj) {
            size_t gcol = bn + wc*WTN + fj*16 + fr;
            if ((int)gcol < ncols) {
                #pragma unroll
                for (int r = 0; r < 4; ++r) {
                    if constexpr (BF16OUT)
                        ((u16*)Cv)[(grow0 + r)*ldc + gcol] = f2bf(acc[fi][fj][r]);
                    else
                        ((float*)Cv)[(grow0 + r)*ldc + gcol] = acc[fi][fj][r];
                }
            }
        }
    }
}

// ---------------- out_proj: depth-2 counted-vmcnt pipeline (1 block/CU, no TLP) ----------------
__global__ __launch_bounds__(256) void k_outproj(const u16* __restrict__ A,
                                                 const u16* __restrict__ B,
                                                 float* __restrict__ C) {
    constexpr int BM = 64, BN = 64, K = 1024, BK = 64, NK = K/BK, NBX = DM/BN;
    constexpr int FM = 2, FN = 2;
    constexpr int CA = 2, CB = 2;          // 4 gl_lds per thread per stage
    constexpr int TA = BM*8, TB = BN*8;
    __shared__ u16 As[3*TA*8];
    __shared__ u16 Bs[3*TB*8];
    int tid = threadIdx.x, lane = tid & 63, wave = tid >> 6;
    int wr = wave >> 1, wc = wave & 1;

    int nb = xcd_swz(blockIdx.x, gridDim.x);
    size_t bm = (size_t)(nb / NBX) * BM, bn = (size_t)(nb % NBX) * BN;

    const u16* sA[CA]; int dA[CA];
    #pragma unroll
    for (int j = 0; j < CA; ++j) {
        int i = j*256 + tid, row = i >> 3, pos = i & 7;
        sA[j] = A + (bm + row)*(size_t)K + (pos ^ (row & 7))*8;
        dA[j] = i*8;
    }
    const u16* sB[CB]; int dB[CB];
    #pragma unroll
    for (int j = 0; j < CB; ++j) {
        int i = j*256 + tid, row = i >> 3, pos = i & 7;
        sB[j] = B + (bn + row)*(size_t)K + (pos ^ (row & 7))*8;
        dB[j] = i*8;
    }

    int fr = lane & 15, kq = lane >> 4;
    int ar[FM], br[FN];
    #pragma unroll
    for (int fi = 0; fi < FM; ++fi) ar[fi] = wr*32 + fi*16 + fr;
    #pragma unroll
    for (int fj = 0; fj < FN; ++fj) br[fj] = wc*32 + fj*16 + fr;

    f32x4 acc[FM][FN];
    #pragma unroll
    for (int fi = 0; fi < FM; ++fi)
        #pragma unroll
        for (int fj = 0; fj < FN; ++fj)
            acc[fi][fj] = (f32x4){0.f,0.f,0.f,0.f};

    auto STAGE = [&](int t, int buf) {
        int k0 = t*BK;
        #pragma unroll
        for (int j = 0; j < CA; ++j) gl_lds16(sA[j] + k0, As + buf*TA*8 + dA[j]);
        #pragma unroll
        for (int j = 0; j < CB; ++j) gl_lds16(sB[j] + k0, Bs + buf*TB*8 + dB[j]);
    };

    // prologue: tiles 0,1 in flight
    STAGE(0, 0);
    STAGE(1, 1);

    #pragma unroll 1
    for (int step = 0; step < NK; ++step) {
        int nxt = step + 2;
        if (nxt < NK) STAGE(nxt, nxt % 3);
        // wait for tile `step`'s loads only; newer stages stay in flight
        if (step < NK-2)       wait_vmcnt<2*(CA+CB)>();
        else if (step == NK-2) wait_vmcnt<CA+CB>();
        else                   wait_vmcnt<0>();
        __builtin_amdgcn_s_barrier();

        const u16* Ab = As + (step % 3)*TA*8;
        const u16* Bb = Bs + (step % 3)*TB*8;
        #pragma unroll
        for (int ks = 0; ks < 2; ++ks) {
            bf16x8 av[FM], bv[FN];
            #pragma unroll
            for (int fi = 0; fi < FM; ++fi)
                av[fi] = *reinterpret_cast<const bf16x8*>(Ab + (ar[fi]*8 + ((ks*4+kq) ^ (ar[fi]&7)))*8);
            #pragma unroll
            for (int fj = 0; fj < FN; ++fj)
                bv[fj] = *reinterpret_cast<const bf16x8*>(Bb + (br[fj]*8 + ((ks*4+kq) ^ (br[fj]&7)))*8);
            #pragma unroll
            for (int fi = 0; fi < FM; ++fi)
                #pragma unroll
                for (int fj = 0; fj < FN; ++fj)
                    acc[fi][fj] = __builtin_amdgcn_mfma_f32_16x16x32_bf16(
                        av[fi], bv[fj], acc[fi][fj], 0, 0, 0);
        }
        __builtin_amdgcn_s_barrier();   // protect buf reuse 3 steps later
    }

    #pragma unroll
    for (int fi = 0; fi < FM; ++fi) {
        size_t grow0 = bm + wr*32 + fi*16 + kq*4;
        #pragma unroll
        for (int fj = 0; fj < FN; ++fj) {
            size_t gcol = bn + wc*32 + fj*16 + fr;
            #pragma unroll
            for (int r = 0; r < 4; ++r)
                C[(grow0 + r)*DM + gcol] = acc[fi][fj][r];
        }
    }
}

// ---------------- depthwise conv + SiLU (bf16 in/out) ----------------
__global__ __launch_bounds__(320) void k_conv(const u16* __restrict__ zx,
                                              const float* __restrict__ cw,
                                              const float* __restrict__ cb,
                                              u16* __restrict__ convo) {
    int row = blockIdx.x;            // b*SEQ + l
    int l   = row & (SEQ-1);
    int c0  = threadIdx.x * 4;

    const float4* cw4 = reinterpret_cast<const float4*>(cw);
    float4 w0 = cw4[c0+0], w1 = cw4[c0+1], w2 = cw4[c0+2], w3 = cw4[c0+3];
    const float* wa0 = &w0.x; const float* wa1 = &w1.x;
    const float* wa2 = &w2.x; const float* wa3 = &w3.x;

    float4 bv = *reinterpret_cast<const float4*>(cb + c0);
    float acc0 = bv.x, acc1 = bv.y, acc2 = bv.z, acc3 = bv.w;

    #pragma unroll
    for (int k = 0; k < 4; ++k) {
        int lk = l - 3 + k;
        if (lk < 0) continue;
        u16x4 v = *reinterpret_cast<const u16x4*>(zx + (size_t)(row-3+k)*DPROJ + DI + c0);
        acc0 += bf2f(v[0]) * wa0[k];
        acc1 += bf2f(v[1]) * wa1[k];
        acc2 += bf2f(v[2]) * wa2[k];
        acc3 += bf2f(v[3]) * wa3[k];
    }
    u16x4 o;
    o[0] = f2bf(acc0 / (1.f + expf(-acc0)));
    o[1] = f2bf(acc1 / (1.f + expf(-acc1)));
    o[2] = f2bf(acc2 / (1.f + expf(-acc2)));
    o[3] = f2bf(acc3 / (1.f + expf(-acc3)));
    *reinterpret_cast<u16x4*>(convo + (size_t)row*CONVD + c0) = o;
}

// ---------------- chunk state via MFMA: S[p][n] = sum_t coef_t*xs[t,p]*B[t,n] ----------------
__global__ __launch_bounds__(256) void k_chunk_state(
    const u16* __restrict__ convo, const float* __restrict__ dtb,
    const float* __restrict__ abuf, u16* __restrict__ Sb,
    float* __restrict__ Pbuf) {
    int nb = xcd_swz(blockIdx.x, gridDim.x);   // h + NH*(c + NCH*b)
    int h  = nb & (NH-1);
    int c  = (nb >> 4) & (NCH-1);
    int b  = nb >> 8;
    int sidx = c + NCH*(h + NH*b);
    int row0 = b*SEQ + c*CHK;
    int tid = threadIdx.x, lane = tid & 63, wave = tid >> 6;
    int wr = wave >> 1, wc = wave & 1;

    __shared__ u16 xsT[64*64];     // rows p, k=t, SLROW=8
    __shared__ u16 BT[128*64];     // rows n, k=t, SLROW=8
    __shared__ float s_coef[CHK];

    int st = tid >> 2, q = tid & 3;
    const u16* r = convo + (size_t)(row0 + st)*CONVD;
    u16x8 xa = *reinterpret_cast<const u16x8*>(r + h*HD + q*16);
    u16x8 xc = *reinterpret_cast<const u16x8*>(r + h*HD + q*16 + 8);
    u16x8 b0 = *reinterpret_cast<const u16x8*>(r + DI + q*32);
    u16x8 b1 = *reinterpret_cast<const u16x8*>(r + DI + q*32 + 8);
    u16x8 b2 = *reinterpret_cast<const u16x8*>(r + DI + q*32 + 16);
    u16x8 b3 = *reinterpret_cast<const u16x8*>(r + DI + q*32 + 24);

    if (tid < CHK) {
        float v = abuf[(size_t)(row0 + tid)*NH + h];
        #pragma unroll
        for (int off = 1; off < 64; off <<= 1) {
            float o = __shfl_up(v, off);
            if (tid >= off) v += o;
        }
        float vend = __shfl(v, 63);
        float dt = dtb[(size_t)(row0 + tid)*NH + h];
        s_coef[tid] = dt * expf(vend - v);
        if (tid == 63) Pbuf[sidx] = expf(vend);
    }
    __syncthreads();

    float cf = s_coef[st];
    #pragma unroll
    for (int e = 0; e < 16; ++e) {
        int p = q*16 + e;
        u16 xv = (e < 8) ? xa[e] : xc[e-8];
        xsT[(p*8 + ((st>>3) ^ (p&7)))*8 + (st&7)] = f2bf(cf * bf2f(xv));
    }
    #pragma unroll
    for (int e = 0; e < 32; ++e) {
        int n = q*32 + e;
        u16 bvv = (e < 8) ? b0[e] : (e < 16) ? b1[e-8] : (e < 24) ? b2[e-16] : b3[e-24];
        BT[(n*8 + ((st>>3) ^ (n&7)))*8 + (st&7)] = bvv;
    }
    __syncthreads();

    int kq = lane >> 4, fr = lane & 15;
    f32x4 acc[2][4];
    #pragma unroll
    for (int fi = 0; fi < 2; ++fi)
        #pragma unroll
        for (int fj = 0; fj < 4; ++fj)
            acc[fi][fj] = (f32x4){0.f,0.f,0.f,0.f};

    #pragma unroll
    for (int ks = 0; ks < 2; ++ks) {
        bf16x8 av[2], bv[4];
        #pragma unroll
        for (int fi = 0; fi < 2; ++fi)
            av[fi] = *reinterpret_cast<const bf16x8*>(xsT + swz_off(wr*32 + fi*16 + fr, ks*4 + kq, 8));
        #pragma unroll
        for (int fj = 0; fj < 4; ++fj)
            bv[fj] = *reinterpret_cast<const bf16x8*>(BT + swz_off(wc*64 + fj*16 + fr, ks*4 + kq, 8));
        #pragma unroll
        for (int fi = 0; fi < 2; ++fi)
            #pragma unroll
            for (int fj = 0; fj < 4; ++fj)
                acc[fi][fj] = __builtin_amdgcn_mfma_f32_16x16x32_bf16(av[fi], bv[fj], acc[fi][fj], 0,0,0);
    }

    u16* outp = Sb + (size_t)sidx*(HD*DS);
    #pragma unroll
    for (int fi = 0; fi < 2; ++fi)
        #pragma unroll
        for (int rr = 0; rr < 4; ++rr) {
            int p = wr*32 + fi*16 + kq*4 + rr;
            #pragma unroll
            for (int fj = 0; fj < 4; ++fj) {
                int n = wc*64 + fj*16 + fr;
                outp[(size_t)p*DS + n] = f2bf(acc[fi][fj][rr]);
            }
        }
}

// ---------------- state pass: parallel over (bh, 8 segments); loads up-front ----------------
__global__ __launch_bounds__(256) void k_state_pass(u16* __restrict__ Sb,
                                                    const float* __restrict__ Pbuf) {
    int bh = blockIdx.x >> 3, seg = blockIdx.x & 7;
    int off = seg*1024 + threadIdx.x*4;
    u16x4 s[NCH];
    #pragma unroll
    for (int cc = 0; cc < NCH; ++cc)
        s[cc] = *reinterpret_cast<const u16x4*>(Sb + ((size_t)(bh*NCH + cc))*(HD*DS) + off);
    float hr[4] = {0.f,0.f,0.f,0.f};
    #pragma unroll
    for (int cc = 0; cc < NCH; ++cc) {
        u16x4 w = { f2bf(hr[0]), f2bf(hr[1]), f2bf(hr[2]), f2bf(hr[3]) };
        *reinterpret_cast<u16x4*>(Sb + ((size_t)(bh*NCH + cc))*(HD*DS) + off) = w;
        float P = Pbuf[bh*NCH + cc];
        #pragma unroll
        for (int j = 0; j < 4; ++j) hr[j] = hr[j]*P + bf2f(s[cc][j]);
    }
}

// ---------------- chunk output via MFMA (swizzled grid, h low bits) ----------------
__global__ __launch_bounds__(256) void k_chunk_out(
    const u16* __restrict__ convo, const float* __restrict__ dtb,
    const float* __restrict__ abuf, const u16* __restrict__ Sb,
    const float* __restrict__ Dp, u16* __restrict__ ybuf) {
    int nb = xcd_swz(blockIdx.x, gridDim.x);
    int h  = nb & (NH-1);
    int c  = (nb >> 4) & (NCH-1);
    int b  = nb >> 8;
    int sidx = c + NCH*(h + NH*b);
    int row0 = b*SEQ + c*CHK;
    int tid = threadIdx.x, lane = tid & 63, wave = tid >> 6;
    int wr = wave >> 1, wc = wave & 1;

    __shared__ u16 Ct[64*128];     // C rows t, k=n, SLROW=16
    __shared__ u16 Bh[64*128];     // B rows s (phase B) then hin rows p (phase D)
    __shared__ u16 Mt[64*64];      // M' rows t, k=s, SLROW=8
    __shared__ u16 dxT[64*64];     // xs rows p, k=s, SLROW=8
    __shared__ float s_cum[CHK];
    __shared__ float s_dt[CHK];

    const u16* cbase = convo + (size_t)row0*CONVD;

    stage64<16>(cbase + DI + DS, CONVD, Ct, tid);
    stage64<16>(cbase + DI,      CONVD, Bh, tid);

    int st = tid >> 2, q = tid & 3;
    u16x8 xr0 = *reinterpret_cast<const u16x8*>(cbase + (size_t)st*CONVD + h*HD + q*16);
    u16x8 xr1 = *reinterpret_cast<const u16x8*>(cbase + (size_t)st*CONVD + h*HD + q*16 + 8);

    if (tid < CHK) {
        float v = abuf[(size_t)(row0 + tid)*NH + h];
        #pragma unroll
        for (int off = 1; off < 64; off <<= 1) {
            float o = __shfl_up(v, off);
            if (tid >= off) v += o;
        }
        s_cum[tid] = v;
        s_dt[tid] = dtb[(size_t)(row0 + tid)*NH + h];
    }
    __syncthreads();   // B1: Ct/Bh staged, cum/dt ready

    // scatter dxT (raw xs; dt folded into M')
    #pragma unroll
    for (int e = 0; e < 16; ++e) {
        int p = q*16 + e;
        u16 xv = (e < 8) ? xr0[e] : xr1[e-8];
        dxT[(p*8 + ((st>>3) ^ (p&7)))*8 + (st&7)] = xv;
    }

    int kq = lane >> 4, fr = lane & 15;

    // phase B: M[t][s] = C_t . B_s (K=128)
    f32x4 macc[2][2];
    #pragma unroll
    for (int fi = 0; fi < 2; ++fi)
        #pragma unroll
        for (int fj = 0; fj < 2; ++fj)
            macc[fi][fj] = (f32x4){0.f,0.f,0.f,0.f};
    #pragma unroll
    for (int ks = 0; ks < 4; ++ks) {
        bf16x8 av[2], bv[2];
        #pragma unroll
        for (int fi = 0; fi < 2; ++fi)
            av[fi] = *reinterpret_cast<const bf16x8*>(Ct + swz_off(wr*32 + fi*16 + fr, ks*4 + kq, 16));
        #pragma unroll
        for (int fj = 0; fj < 2; ++fj)
            bv[fj] = *reinterpret_cast<const bf16x8*>(Bh + swz_off(wc*32 + fj*16 + fr, ks*4 + kq, 16));
        #pragma unroll
        for (int fi = 0; fi < 2; ++fi)
            #pragma unroll
            for (int fj = 0; fj < 2; ++fj)
                macc[fi][fj] = __builtin_amdgcn_mfma_f32_16x16x32_bf16(av[fi], bv[fj], macc[fi][fj], 0,0,0);
    }

    // mask + decay + dt-fold, scatter M' (bf16)
    #pragma unroll
    for (int fi = 0; fi < 2; ++fi)
        #pragma unroll
        for (int rr = 0; rr < 4; ++rr) {
            int t = wr*32 + fi*16 + kq*4 + rr;
            float cumt = s_cum[t];
            #pragma unroll
            for (int fj = 0; fj < 2; ++fj) {
                int s = wc*32 + fj*16 + fr;
                float val = (s <= t) ? macc[fi][fj][rr] * expf(cumt - s_cum[s]) * s_dt[s] : 0.f;
                Mt[(t*8 + ((s>>3) ^ (t&7)))*8 + (s&7)] = f2bf(val);
            }
        }
    __syncthreads();   // B2: Mt/dxT complete, Bh consumed

    // stage hin into Bh (rows p, k=n)
    stage64<16>(Sb + (size_t)sidx*(HD*DS), DS, Bh, tid);

    // phase C: Y[t][p] = sum_s M'[t][s]*xs[s][p]  (K=64)
    f32x4 accY[2][2];
    #pragma unroll
    for (int fi = 0; fi < 2; ++fi)
        #pragma unroll
        for (int fj = 0; fj < 2; ++fj)
            accY[fi][fj] = (f32x4){0.f,0.f,0.f,0.f};
    #pragma unroll
    for (int ks = 0; ks < 2; ++ks) {
        bf16x8 av[2], bv[2];
        #pragma unroll
        for (int fi = 0; fi < 2; ++fi)
            av[fi] = *reinterpret_cast<const bf16x8*>(Mt + swz_off(wr*32 + fi*16 + fr, ks*4 + kq, 8));
        #pragma unroll
        for (int fj = 0; fj < 2; ++fj)
            bv[fj] = *reinterpret_cast<const bf16x8*>(dxT + swz_off(wc*32 + fj*16 + fr, ks*4 + kq, 8));
        #pragma unroll
        for (int fi = 0; fi < 2; ++fi)
            #pragma unroll
            for (int fj = 0; fj < 2; ++fj)
                accY[fi][fj] = __builtin_amdgcn_mfma_f32_16x16x32_bf16(av[fi], bv[fj], accY[fi][fj], 0,0,0);
    }
    __syncthreads();   // B3: hin staged

    // phase D: cross[t][p] = C_t . hin[p]  (K=128)
    f32x4 accD[2][2];
    #pragma unroll
    for (int fi = 0; fi < 2; ++fi)
        #pragma unroll
        for (int fj = 0; fj < 2; ++fj)
            accD[fi][fj] = (f32x4){0.f,0.f,0.f,0.f};
    #pragma unroll
    for (int ks = 0; ks < 4; ++ks) {
        bf16x8 av[2], bv[2];
        #pragma unroll
        for (int fi = 0; fi < 2; ++fi)
            av[fi] = *reinterpret_cast<const bf16x8*>(Ct + swz_off(wr*32 + fi*16 + fr, ks*4 + kq, 16));
        #pragma unroll
        for (int fj = 0; fj < 2; ++fj)
            bv[fj] = *reinterpret_cast<const bf16x8*>(Bh + swz_off(wc*32 + fj*16 + fr, ks*4 + kq, 16));
        #pragma unroll
        for (int fi = 0; fi < 2; ++fi)
            #pragma unroll
            for (int fj = 0; fj < 2; ++fj)
                accD[fi][fj] = __builtin_amdgcn_mfma_f32_16x16x32_bf16(av[fi], bv[fj], accD[fi][fj], 0,0,0);
    }

    // epilogue: y = Y + e^{cum_t}*cross + D*xs
    float Dv = Dp[h];
    #pragma unroll
    for (int fi = 0; fi < 2; ++fi)
        #pragma unroll
        for (int rr = 0; rr < 4; ++rr) {
            int t = wr*32 + fi*16 + kq*4 + rr;
            float et = expf(s_cum[t]);
            #pragma unroll
            for (int fj = 0; fj < 2; ++fj) {
                int p = wc*32 + fj*16 + fr;
                float xs = bf2f(cbase[(size_t)t*CONVD + h*HD + p]);
                float y = accY[fi][fj][rr] + et*accD[fi][fj][rr] + Dv*xs;
                ybuf[(size_t)(row0 + t)*DI + h*HD + p] = f2bf(y);
            }
        }
}

// ---------------- gate + RMSNorm (bf16 in, bf16 out) ----------------
__global__ __launch_bounds__(256) void k_gate(const u16* __restrict__ zx,
                                              const u16* __restrict__ ybuf,
                                              const float* __restrict__ nw,
                                              u16* __restrict__ g) {
    int row = blockIdx.x;
    int t = threadIdx.x;
    const u16* zr = zx + (size_t)row*DPROJ;
    const u16* yr = ybuf + (size_t)row*DI;

    u16x4 zv = *reinterpret_cast<const u16x4*>(zr + t*4);
    u16x4 yv = *reinterpret_cast<const u16x4*>(yr + t*4);
    float gv[4];
    float ss = 0.f;
    #pragma unroll
    for (int j = 0; j < 4; ++j) {
        float z = bf2f(zv[j]), y = bf2f(yv[j]);
        float sz = z / (1.f + expf(-z));
        float gg = y * sz;
        gv[j] = gg;
        ss += gg*gg;
    }
    ss += __shfl_xor(ss, 1);
    ss += __shfl_xor(ss, 2);
    ss += __shfl_xor(ss, 4);
    ss += __shfl_xor(ss, 8);
    ss += __shfl_xor(ss, 16);
    ss += __shfl_xor(ss, 32);
    __shared__ float ls[4];
    if ((t & 63) == 0) ls[t >> 6] = ss;
    __syncthreads();
    float tot = ls[0] + ls[1] + ls[2] + ls[3];
    float scale = rsqrtf(tot * (1.f/DI) + 1e-5f);

    float4 nv = *reinterpret_cast<const float4*>(nw + t*4);
    const float* na = &nv.x;
    u16x4 og = { f2bf(gv[0]*scale*na[0]), f2bf(gv[1]*scale*na[1]),
                 f2bf(gv[2]*scale*na[2]), f2bf(gv[3]*scale*na[3]) };
    *reinterpret_cast<u16x4*>(g + (size_t)row*DI + t*4) = og;
}

extern "C" void kernel_launch(void* const* d_in, const int* in_sizes, int n_in,
                              void* d_out, int out_size, void* d_ws, size_t ws_size,
                              hipStream_t stream) {
    const float* x         = (const float*)d_in[0];
    const float* in_proj_w = (const float*)d_in[1];
    const float* conv_w    = (const float*)d_in[2];
    const float* conv_b    = (const float*)d_in[3];
    const float* dt_bias   = (const float*)d_in[4];
    const float* A_log     = (const float*)d_in[5];
    const float* Dp        = (const float*)d_in[6];
    const float* norm_w    = (const float*)d_in[7];
    const float* out_proj_w= (const float*)d_in[8];
    float* out = (float*)d_out;

    char* p = (char*)d_ws;
    u16*   zxb   = (u16*)p;   p += (size_t)ROWS*DPROJ*2;
    u16*   convo = (u16*)p;   p += (size_t)ROWS*CONVD*2;
    float* dtb   = (float*)p; p += (size_t)ROWS*NH*4;
    float* abuf  = (float*)p; p += (size_t)ROWS*NH*4;
    u16*   ybuf  = (u16*)p;   p += (size_t)ROWS*DI*2;
    u16*   xb    = (u16*)p;   p += (size_t)ROWS*DM*2;
    u16*   Wb    = (u16*)p;   p += (size_t)NPAD*DM*2;
    u16*   Wob   = (u16*)p;   p += (size_t)DM*DI*2;
    u16*   Sb    = (u16*)p;   p += (size_t)BATCH*NH*NCH*HD*DS*2;
    float* Pbuf  = (float*)p; p += 512*4;
    u16*   gb    = (u16*)p;   p += (size_t)ROWS*DI*2;

    k_prep<<<1888, 256, 0, stream>>>(x, in_proj_w, out_proj_w, dt_bias, A_log,
                                     xb, Wb, Wob, dtb, abuf);

    // in_proj: M=2048 (BM=64), N=2432 (BN=128), K=512; 1D grid 608 = 8 XCD x 76
    k_gemm<64,128,512,19,true><<<(NPAD/128)*(ROWS/64), 256, 0, stream>>>(xb, Wb, zxb, DPROJ, DPROJ);

    k_conv<<<ROWS, CONVD/4, 0, stream>>>(zxb, conv_w, conv_b, convo);

    k_chunk_state<<<BATCH*NH*NCH, 256, 0, stream>>>(convo, dtb, abuf, Sb, Pbuf);
    k_state_pass <<<BATCH*NH*8, 256, 0, stream>>>(Sb, Pbuf);
    k_chunk_out  <<<BATCH*NH*NCH, 256, 0, stream>>>(convo, dtb, abuf, Sb, Dp, ybuf);

    k_gate<<<ROWS, 256, 0, stream>>>(zxb, ybuf, norm_w, gb);

    // out_proj: M=2048 (BM=64), N=512 (BN=64), K=1024; depth-2 counted-vmcnt; grid 256 = 1/CU
    k_outproj<<<(DM/64)*(ROWS/64), 256, 0, stream>>>(gb, Wob, out);
}